// Round 11
// baseline (259.933 us; speedup 1.0000x reference)
//
#include <hip/hip_runtime.h>

#define W_    256
#define H_    128
#define HW_   32768
#define NB    4
#define NA    5
#define NC    64
#define NIMG  20
#define EPS_  1e-6f

// ---------- bilinear warp taps (matches reference affine_grid + grid_sample) ----------
struct Taps { int o00,o01,o10,o11; float w00,w01,w10,w11; };

__device__ inline void proj_pt(float M0,float M1,float M2,float M3,float M4,float M5,
                               int h,int w,float&px,float&py){
  float gx = 2.0f*((float)w+0.5f)/(float)W_ - 1.0f;
  float gy = 2.0f*((float)h+0.5f)/(float)H_ - 1.0f;
  float X = M0*gx + M1*gy + M2;
  float Y = M3*gx + M4*gy + M5;
  px = ((X+1.0f)*(float)W_ - 1.0f)*0.5f;
  py = ((Y+1.0f)*(float)H_ - 1.0f)*0.5f;
}

__device__ inline Taps make_taps(const float* __restrict__ M, int h, int w){
  float px,py; proj_pt(M[0],M[1],M[2],M[3],M[4],M[5],h,w,px,py);
  float x0f=floorf(px), y0f=floorf(py);
  float wx1=px-x0f, wx0=1.f-wx1, wy1=py-y0f, wy0=1.f-wy1;
  int x0=(int)x0f, y0=(int)y0f, x1=x0+1, y1=y0+1;
  bool vx0=(x0>=0)&&(x0<W_), vx1=(x1>=0)&&(x1<W_);
  bool vy0=(y0>=0)&&(y0<H_), vy1=(y1>=0)&&(y1<H_);
  int cx0=min(max(x0,0),W_-1), cx1=min(max(x1,0),W_-1);
  int cy0=min(max(y0,0),H_-1), cy1=min(max(y1,0),H_-1);
  Taps t;
  t.o00=cy0*W_+cx0; t.o01=cy0*W_+cx1; t.o10=cy1*W_+cx0; t.o11=cy1*W_+cx1;
  t.w00=(vy0&&vx0)?(wy0*wx0):0.f;
  t.w01=(vy0&&vx1)?(wy0*wx1):0.f;
  t.w10=(vy1&&vx0)?(wy1*wx0):0.f;
  t.w11=(vy1&&vx1)?(wy1*wx1):0.f;
  return t;
}

__device__ inline float clip01(float v){ return fminf(fmaxf(v,0.f),1.f); }
__device__ inline float sigmoidf_(float v){
  if (v>=0.f){ float e=expf(-v); return 1.f/(1.f+e); }
  float e=expf(v); return e/(1.f+e);
}
__device__ inline float quantv(int cnt, float q, float vlo, float vhi){
  if (cnt<=0) return 0.f;
  float pos = q*(float)(cnt-1);
  float frac = pos - floorf(pos);
  return vlo + frac*(vhi-vlo);
}
__device__ inline float ge_f(float t, float lo, float hi){
  return clip01((t-lo)/(hi-lo+EPS_));
}
__device__ inline float sel4(float4 q, int i){
  return i==0 ? q.x : (i==1 ? q.y : (i==2 ? q.z : q.w));
}

#define SBAR __builtin_amdgcn_sched_barrier(0)

// ---------- K0: zero the effective-rate counter ----------
__global__ void k_init(int* counters){ if (threadIdx.x==0) counters[0] = 0; }

// ---------- K1a: source-domain Gram maps, interleaved 32B records ----------
// 1 wave per image row. XCD-swizzled (2560 % 8 == 0, bijective) so consecutive
// rows share an XCD -> row r+1's 'b' read L2-hits when block r+1 reads it as 'a'.
__global__ __launch_bounds__(64) void k_gram(
  const float* __restrict__ x, float* __restrict__ gram)
{
  int lane = threadIdx.x;
  int bx = blockIdx.x;              // 0..2559
  int lin = (bx&7)*(NIMG*H_/8) + (bx>>3);
  int bn = lin >> 7;
  int r  = lin & 127;
  int rn = min(r+1, H_-1);          // clamped next row (coeff-dead at r=127, finite)
  int col = lane<<2;
  const float* xb = x + (size_t)bn*NC*HW_;
  float4 aA={0,0,0,0}, aBx={0,0,0,0}, aBy={0,0,0,0}, aBd1={0,0,0,0}, aBd2={0,0,0,0};
  #pragma unroll 4
  for (int c=0;c<NC;++c){
    const float* pc = xb + (size_t)c*HW_;
    float4 a = *reinterpret_cast<const float4*>(pc + r*W_  + col);
    float4 b = *reinterpret_cast<const float4*>(pc + rn*W_ + col);
    float axn = __shfl(a.x, lane+1, 64);   // lane63 wraps: finite, coeff-dead (col 255)
    float bxn = __shfl(b.x, lane+1, 64);
    aA.x  = fmaf(a.x,a.x,aA.x);  aA.y  = fmaf(a.y,a.y,aA.y);
    aA.z  = fmaf(a.z,a.z,aA.z);  aA.w  = fmaf(a.w,a.w,aA.w);
    aBx.x = fmaf(a.x,a.y,aBx.x); aBx.y = fmaf(a.y,a.z,aBx.y);
    aBx.z = fmaf(a.z,a.w,aBx.z); aBx.w = fmaf(a.w,axn,aBx.w);
    aBy.x = fmaf(a.x,b.x,aBy.x); aBy.y = fmaf(a.y,b.y,aBy.y);
    aBy.z = fmaf(a.z,b.z,aBy.z); aBy.w = fmaf(a.w,b.w,aBy.w);
    aBd1.x= fmaf(a.x,b.y,aBd1.x);aBd1.y= fmaf(a.y,b.z,aBd1.y);
    aBd1.z= fmaf(a.z,b.w,aBd1.z);aBd1.w= fmaf(a.w,bxn,aBd1.w);
    aBd2.x= fmaf(a.y,b.x,aBd2.x);aBd2.y= fmaf(a.z,b.y,aBd2.y);
    aBd2.z= fmaf(a.w,b.z,aBd2.z);aBd2.w= fmaf(axn,b.w,aBd2.w);
  }
  float* g0 = gram + (((size_t)bn*HW_ + (size_t)r*W_ + col)<<3);
  float4 lo,hi;
  lo.x=aA.x; lo.y=aBx.x; lo.z=aBy.x; lo.w=aBd1.x; hi.x=aBd2.x; hi.y=0; hi.z=0; hi.w=0;
  *reinterpret_cast<float4*>(g0+ 0)=lo; *reinterpret_cast<float4*>(g0+ 4)=hi;
  lo.x=aA.y; lo.y=aBx.y; lo.z=aBy.y; lo.w=aBd1.y; hi.x=aBd2.y;
  *reinterpret_cast<float4*>(g0+ 8)=lo; *reinterpret_cast<float4*>(g0+12)=hi;
  lo.x=aA.z; lo.y=aBx.z; lo.z=aBy.z; lo.w=aBd1.z; hi.x=aBd2.z;
  *reinterpret_cast<float4*>(g0+16)=lo; *reinterpret_cast<float4*>(g0+20)=hi;
  lo.x=aA.w; lo.y=aBx.w; lo.z=aBy.w; lo.w=aBd1.w; hi.x=aBd2.w;
  *reinterpret_cast<float4*>(g0+24)=lo; *reinterpret_cast<float4*>(g0+28)=hi;
}

// ---------- K1b: warp + stats from Gram records ----------
__global__ __launch_bounds__(256) void k_warp2(
  const float* __restrict__ psm, const float* __restrict__ nam,
  const float* __restrict__ gram,
  float* __restrict__ vis, float* __restrict__ scraw, float* __restrict__ sfull,
  float* __restrict__ energy)
{
  int w = threadIdx.x, h = blockIdx.x, bn = blockIdx.y;
  int b = bn/NA, n = bn - b*NA;
  const float* M = nam + (size_t)(b*NA*NA + n)*6;
  float px,py; proj_pt(M[0],M[1],M[2],M[3],M[4],M[5],h,w,px,py);
  float x0f=floorf(px), y0f=floorf(py);
  float wx1=px-x0f, wx0=1.f-wx1, wy1=py-y0f, wy0=1.f-wy1;
  int x0=(int)x0f, y0=(int)y0f, x1=x0+1, y1=y0+1;
  bool vx0=(x0>=0)&&(x0<W_), vx1=(x1>=0)&&(x1<W_);
  bool vy0=(y0>=0)&&(y0<H_), vy1=(y1>=0)&&(y1<H_);
  int cx0=min(max(x0,0),W_-1), cx1=min(max(x1,0),W_-1);
  int cy0=min(max(y0,0),H_-1), cy1=min(max(y1,0),H_-1);
  float w00=(vy0&&vx0)?(wy0*wx0):0.f;
  float w01=(vy0&&vx1)?(wy0*wx1):0.f;
  float w10=(vy1&&vx0)?(wy1*wx0):0.f;
  float w11=(vy1&&vx1)?(wy1*wx1):0.f;
  int i00=cy0*W_+cx0, i01=cy0*W_+cx1, i10=cy1*W_+cx0, i11=cy1*W_+cx1;
  float vv = w00+w01+w10+w11;

  const float* p0 = psm + ((size_t)bn*2+0)*HW_;
  const float* p1 = psm + ((size_t)bn*2+1)*HW_;
  float c0 = w00*p0[i00]+w01*p0[i01]+w10*p0[i10]+w11*p0[i11];
  float c1 = w00*p1[i00]+w01*p1[i01]+w10*p1[i10]+w11*p1[i11];

  const float* G = gram + ((size_t)bn*HW_<<3);
  float4 R00 = *reinterpret_cast<const float4*>(G + ((size_t)i00<<3)); // A,Bx,By,D1
  float  D2  = G[((size_t)i00<<3)+4];
  float4 R01 = *reinterpret_cast<const float4*>(G + ((size_t)i01<<3));
  float4 R10 = *reinterpret_cast<const float4*>(G + ((size_t)i10<<3));
  float  A11 = G[(size_t)i11<<3];
  float e = w00*w00*R00.x + w01*w01*R01.x + w10*w10*R10.x + w11*w11*A11
          + 2.0f*( w00*w01*R00.y + w10*w11*R10.y
                 + w00*w10*R00.z + w01*w11*R01.z
                 + w00*w11*R00.w + w01*w10*D2 );

  size_t idx = (size_t)bn*HW_ + (size_t)h*W_ + w;
  vis[idx]=vv;
  scraw[idx]=fmaxf(sigmoidf_(c0), sigmoidf_(c1));
  sfull[idx]=(clip01(c0)+clip01(c1))*0.5f;
  energy[idx]=e*(1.0f/64.0f);
}

// ---------- K1-mono (fallback if ws too small): R7 proven kernel ----------
#define TWm    32
#define THm    16
#define CAPm   2048
#define TRIPSm 2
#define NBUFm  3
__global__ __launch_bounds__(256) void k_warp_stats_mono(
  const float* __restrict__ x, const float* __restrict__ psm, const float* __restrict__ nam,
  float* __restrict__ vis, float* __restrict__ scraw, float* __restrict__ sfull,
  float* __restrict__ energy)
{
  __shared__ __align__(16) float smem[NBUFm][CAPm];
  int tid = threadIdx.x;
  int tx = blockIdx.x, ty = blockIdx.y, bn = blockIdx.z;
  int b = bn/NA, n = bn - b*NA;
  const float* M = nam + (size_t)(b*NA*NA + n)*6;
  float M0=M[0],M1=M[1],M2=M[2],M3=M[3],M4=M[4],M5=M[5];
  int tw0 = tx*TWm, th0 = ty*THm;
  int r  = tid>>4;
  int cb = (tid&15)<<1;
  int h  = th0 + r;
  int w0 = tw0 + cb;
  float pxa,pya,pxb,pyb,pxc,pyc,pxd,pyd;
  proj_pt(M0,M1,M2,M3,M4,M5, th0,       tw0,       pxa,pya);
  proj_pt(M0,M1,M2,M3,M4,M5, th0,       tw0+TWm-1, pxb,pyb);
  proj_pt(M0,M1,M2,M3,M4,M5, th0+THm-1, tw0,       pxc,pyc);
  proj_pt(M0,M1,M2,M3,M4,M5, th0+THm-1, tw0+TWm-1, pxd,pyd);
  float pxmin=fminf(fminf(pxa,pxb),fminf(pxc,pxd));
  float pxmax=fmaxf(fmaxf(pxa,pxb),fmaxf(pxc,pxd));
  float pymin=fminf(fminf(pya,pyb),fminf(pyc,pyd));
  float pymax=fmaxf(fmaxf(pya,pyb),fmaxf(pyc,pyd));
  int xs = min(max((int)floorf(pxmin)-1, 0), W_-1);
  int xe = min(max((int)floorf(pxmax)+2, 0), W_-1);
  int ys = min(max((int)floorf(pymin)-1, 0), H_-1);
  int ye = min(max((int)floorf(pymax)+2, 0), H_-1);
  int xs4 = xs & ~3;
  int bwid = xe - xs4 + 1, bh = ye - ys + 1;
  int nck = (bwid+3)>>2;
  int bwp = nck<<2;
  int E2 = bh*bwp;
  bool ok = (E2 <= CAPm);
  float vvv[2], w00_[2],w01_[2],w10_[2],w11_[2];
  int   gx0[2],gx1[2],gy0c[2],gy1c[2];
  int   rx0[2]; bool vx0f[2];
  #pragma unroll
  for (int k=0;k<2;++k){
    float px,py; proj_pt(M0,M1,M2,M3,M4,M5, h, w0+k, px,py);
    float x0f=floorf(px), y0f=floorf(py);
    float wx1=px-x0f, wx0=1.f-wx1, wy1=py-y0f, wy0=1.f-wy1;
    int x0=(int)x0f, y0=(int)y0f, x1=x0+1, y1=y0+1;
    bool vx0=(x0>=0)&&(x0<W_), vx1=(x1>=0)&&(x1<W_);
    bool vy0=(y0>=0)&&(y0<H_), vy1=(y1>=0)&&(y1<H_);
    float w00=(vy0&&vx0)?(wy0*wx0):0.f;
    float w01=(vy0&&vx1)?(wy0*wx1):0.f;
    float w10=(vy1&&vx0)?(wy1*wx0):0.f;
    float w11=(vy1&&vx1)?(wy1*wx1):0.f;
    w00_[k]=w00; w01_[k]=w01; w10_[k]=w10; w11_[k]=w11;
    vvv[k]=w00+w01+w10+w11;
    gx0[k]=min(max(x0,0),W_-1); gx1[k]=min(max(x1,0),W_-1);
    gy0c[k]=min(max(y0,0),H_-1); gy1c[k]=min(max(y1,0),H_-1);
    rx0[k]=x0; vx0f[k]=vx0;
  }
  size_t idx = (size_t)bn*HW_ + (size_t)h*W_ + w0;
  float acc[2] = {0.f,0.f};
  int srcoff[TRIPSm]; int ldsbase = (tid>>6)<<6;
  const float* xb0 = x + (size_t)bn*NC*HW_ + (size_t)ys*W_ + xs4;
  if (ok){
    int totq = bh*nck;
    unsigned magic = (unsigned)((0x100000000ULL + (unsigned)nck - 1) / (unsigned)nck);
    int colcap = (W_-4) - xs4;
    #pragma unroll
    for (int k=0;k<TRIPSm;++k){
      int qq = min(tid + (k<<8), totq-1);
      int row = (int)__umulhi((unsigned)qq, magic);
      int col = (qq - row*nck)<<2;
      srcoff[k] = row*W_ + min(col, colcap);
    }
  }
  auto issue = [&](int ch, int bsel){
    const float* src = xb0 + (size_t)ch*HW_;
    #pragma unroll
    for (int k=0;k<TRIPSm;++k){
      __builtin_amdgcn_global_load_lds(
        (const __attribute__((address_space(1))) void*)(src + srcoff[k]),
        (__attribute__((address_space(3))) void*)&smem[bsel][(ldsbase + (k<<8))<<2],
        16, 0, 0);
    }
  };
  if (ok){ issue(0,0); issue(1,1); }
  {
    const float* p0 = psm + ((size_t)bn*2+0)*HW_;
    const float* p1 = psm + ((size_t)bn*2+1)*HW_;
    #pragma unroll
    for (int k=0;k<2;++k){
      int o00=gy0c[k]*W_+gx0[k], o01=gy0c[k]*W_+gx1[k];
      int o10=gy1c[k]*W_+gx0[k], o11=gy1c[k]*W_+gx1[k];
      float c0 = w00_[k]*p0[o00]+w01_[k]*p0[o01]+w10_[k]*p0[o10]+w11_[k]*p0[o11];
      float c1 = w00_[k]*p1[o00]+w01_[k]*p1[o01]+w10_[k]*p1[o10]+w11_[k]*p1[o11];
      vis[idx+k]   = vvv[k];
      scraw[idx+k] = fmaxf(sigmoidf_(c0), sigmoidf_(c1));
      sfull[idx+k] = (clip01(c0)+clip01(c1))*0.5f;
    }
  }
  if (ok){
    int a0[2],a1[2]; float e0[2],e1[2],f0[2],f1[2];
    #pragma unroll
    for (int k=0;k<2;++k){
      int bc = min(max(rx0[k]-xs4,0), bwp-1);
      a0[k] = (gy0c[k]-ys)*bwp + bc;
      a1[k] = (gy1c[k]-ys)*bwp + bc;
      bool v0 = vx0f[k];
      e0[k] = v0 ? w00_[k] : w01_[k];
      e1[k] = v0 ? w01_[k] : 0.f;
      f0[k] = v0 ? w10_[k] : w11_[k];
      f1[k] = v0 ? w11_[k] : 0.f;
    }
    #pragma unroll 1
    for (int c=0;c<NC;++c){
      asm volatile("s_waitcnt vmcnt(2)" ::: "memory"); SBAR;
      __builtin_amdgcn_s_barrier(); SBAR;
      {
        int nc2 = c+2 < NC ? c+2 : NC-1;
        issue(nc2, (c+2)%NBUFm);
      }
      const float* B = smem[c%NBUFm];
      #pragma unroll
      for (int k=0;k<2;++k){
        float r00=B[a0[k]], r01=B[a0[k]+1];
        float r10=B[a1[k]], r11=B[a1[k]+1];
        float v = e0[k]*r00 + e1[k]*r01 + f0[k]*r10 + f1[k]*r11;
        acc[k] += v*v;
      }
    }
    asm volatile("s_waitcnt vmcnt(0)" ::: "memory");
  } else {
    const float* xb = x + (size_t)bn*NC*HW_;
    int go00[2],go01[2],go10[2],go11[2];
    #pragma unroll
    for (int k=0;k<2;++k){
      go00[k]=gy0c[k]*W_+gx0[k]; go01[k]=gy0c[k]*W_+gx1[k];
      go10[k]=gy1c[k]*W_+gx0[k]; go11[k]=gy1c[k]*W_+gx1[k];
    }
    for (int c=0;c<NC;++c){
      const float* pc = xb + (size_t)c*HW_;
      #pragma unroll
      for (int k=0;k<2;++k){
        float v = w00_[k]*pc[go00[k]] + w01_[k]*pc[go01[k]]
                + w10_[k]*pc[go10[k]] + w11_[k]*pc[go11[k]];
        acc[k] += v*v;
      }
    }
  }
  #pragma unroll
  for (int k=0;k<2;++k) energy[idx+k] = acc[k]*(1.0f/64.0f);
}

// ---------- K3: radix-select, ONE BLOCK PER (image, rank); count computed in-block ----------
#define OS_T 1024
__global__ __launch_bounds__(1024) void k_select(
    const float* __restrict__ energy, const float* __restrict__ scraw,
    const float* __restrict__ ppre, const float* __restrict__ vis,
    float* __restrict__ statsE, float* __restrict__ statsC, float* __restrict__ statsP,
    int mode)
{
  __shared__ int hist[16*256];
  __shared__ int cum[256];
  __shared__ unsigned s_pre;
  __shared__ int s_rk;
  __shared__ int s_cnt;
  int tid = threadIdx.x;
  int t = blockIdx.x;

  const float* d; const float* m; float* stats; int img, r;
  if (mode==0){
    bool isC = (t>=96); int tt = isC ? t-96 : t;
    if (tt<80){ img=tt>>2; r=tt&3; } else { int j=tt-80; img=(j>>2)*NA; r=4+(j&3); }
    d = (isC?scraw:energy) + (size_t)img*HW_;
    m = vis + (size_t)img*HW_;
    stats = isC?statsC:statsE;
  } else {
    img = t>>2; r = t&3;
    d = ppre + (size_t)img*HW_;
    m = vis + (size_t)(img*NA)*HW_;
    stats = statsP;
  }

  if (tid==0) s_cnt = 0;
  __syncthreads();

  unsigned key[32];
  int cc = 0;
  #pragma unroll
  for (int k=0;k<32;++k){
    int i = tid + (k<<10);
    unsigned u = __float_as_uint(d[i]);
    unsigned kk = (u & 0x80000000u) ? ~u : (u|0x80000000u);
    bool valid = (m[i] > 0.f);
    key[k] = valid ? kk : 0xFFFFFFFFu;
    cc += valid ? 1 : 0;
  }
  #pragma unroll
  for (int off=32;off;off>>=1) cc += __shfl_down(cc,off);
  if ((tid&63)==0) atomicAdd(&s_cnt, cc);
  __syncthreads();
  int cnt = s_cnt;
  int cm1 = cnt>0 ? cnt-1 : 0;
  float p2 = 0.2f*(float)cm1, p8 = 0.8f*(float)cm1;
  int l2=(int)floorf(p2), h2=(int)ceilf(p2), l8=(int)floorf(p8), h8=(int)ceilf(p8);
  int rank;
  switch(r){
    case 0: rank=l2; break;      case 1: rank=h2; break;
    case 2: rank=l8; break;      case 3: rank=h8; break;
    case 4: rank=cm1-l2; break;  case 5: rank=cm1-h2; break;
    case 6: rank=cm1-l8; break;  default: rank=cm1-h8; break;
  }
  if (tid==0){ s_pre=0u; s_rk=rank; }
  int slice = tid & 15;
  #pragma unroll
  for (int round=0; round<4; ++round){
    const int shift = 24 - 8*round;
    for (int i=tid;i<16*256;i+=OS_T) hist[i]=0;
    __syncthreads();
    unsigned pre = s_pre;
    if (round==0){
      #pragma unroll
      for (int k=0;k<32;++k)
        atomicAdd(&hist[slice*256 + (key[k]>>24)], 1);
    } else {
      #pragma unroll
      for (int k=0;k<32;++k)
        if ((key[k]>>(shift+8)) == pre)
          atomicAdd(&hist[slice*256 + ((key[k]>>shift)&255u)], 1);
    }
    __syncthreads();
    if (tid<256){
      int tt2=0;
      #pragma unroll
      for (int s=0;s<16;++s) tt2 += hist[s*256+tid];
      cum[tid]=tt2;
    }
    __syncthreads();
    if (tid<64){
      int c0=cum[4*tid+0],c1=cum[4*tid+1],c2=cum[4*tid+2],c3=cum[4*tid+3];
      int i0=c0, i1=i0+c1, i2=i1+c2, i3=i2+c3;
      int tot=i3, scan=tot;
      #pragma unroll
      for (int off=1;off<64;off<<=1){ int v=__shfl_up(scan,off); if (tid>=off) scan+=v; }
      int base = scan-tot;
      int rk = s_rk; unsigned pr = s_pre;
      int b0=base, b1=base+i0, b2=base+i1, b3=base+i2, e3=base+i3;
      if      (rk>=b0 && rk<b1){ s_pre=(pr<<8)|(unsigned)(4*tid+0); s_rk=rk-b0; }
      else if (rk>=b1 && rk<b2){ s_pre=(pr<<8)|(unsigned)(4*tid+1); s_rk=rk-b1; }
      else if (rk>=b2 && rk<b3){ s_pre=(pr<<8)|(unsigned)(4*tid+2); s_rk=rk-b2; }
      else if (rk>=b3 && rk<e3){ s_pre=(pr<<8)|(unsigned)(4*tid+3); s_rk=rk-b3; }
    }
    __syncthreads();
  }
  if (tid==0){
    unsigned k = s_pre;
    unsigned u = (k & 0x80000000u) ? (k & 0x7FFFFFFFu) : ~k;
    stats[img*16 + 1 + r] = __uint_as_float(u);
    if (r==0) stats[img*16] = (float)cnt;
  }
}

// ---------- K4: per-batch scalar params from order stats ----------
__global__ void k_params(const float* __restrict__ statsE, const float* __restrict__ statsC,
                         float* __restrict__ params){
  int b = threadIdx.x;
  if (b>=NB) return;
  float* pr = params + b*32;
  for (int n=0;n<NA;++n){
    const float* sE = statsE + (size_t)(b*NA+n)*16;
    const float* sC = statsC + (size_t)(b*NA+n)*16;
    int cE=(int)sE[0], cC=(int)sC[0];
    pr[n]    = quantv(cE,0.2f,sE[1],sE[2]);
    pr[5+n]  = quantv(cE,0.8f,sE[3],sE[4]);
    pr[10+n] = quantv(cC,0.2f,sC[1],sC[2]);
    pr[15+n] = quantv(cC,0.8f,sC[3],sC[4]);
  }
  const float* sE0 = statsE + (size_t)(b*NA)*16;
  const float* sC0 = statsC + (size_t)(b*NA)*16;
  float loe=pr[0], hie=pr[5], loc=pr[10], hic=pr[15];
  float de_lo=0.f,de_hi=0.f,ke=0.f, dc_lo=0.f,dc_hi=0.f,kc=0.f;
  int c0=(int)sE0[0];
  if (c0>0){
    int cm1=c0-1;
    float pos2=0.2f*(float)cm1, pos8=0.8f*(float)cm1;
    float f2=pos2-floorf(pos2), f8=pos8-floorf(pos8);
    float a,bb;
    a=1.f-ge_f(sE0[5],loe,hie); bb=1.f-ge_f(sE0[6],loe,hie); de_lo=a+f2*(bb-a);
    a=1.f-ge_f(sE0[7],loe,hie); bb=1.f-ge_f(sE0[8],loe,hie); de_hi=a+f8*(bb-a);
    a=ge_f(sE0[1],loe,hie);     bb=ge_f(sE0[2],loe,hie);     ke  =a+f2*(bb-a);
  }
  int c0c=(int)sC0[0];
  if (c0c>0){
    int cm1=c0c-1;
    float pos2=0.2f*(float)cm1, pos8=0.8f*(float)cm1;
    float f2=pos2-floorf(pos2), f8=pos8-floorf(pos8);
    float a,bb;
    a=1.f-ge_f(sC0[5],loc,hic); bb=1.f-ge_f(sC0[6],loc,hic); dc_lo=a+f2*(bb-a);
    a=1.f-ge_f(sC0[7],loc,hic); bb=1.f-ge_f(sC0[8],loc,hic); dc_hi=a+f8*(bb-a);
    a=ge_f(sC0[1],loc,hic);     bb=ge_f(sC0[2],loc,hic);     kc  =a+f2*(bb-a);
  }
  pr[20]=de_lo; pr[21]=de_hi; pr[22]=dc_lo; pr[23]=dc_hi; pr[24]=ke; pr[25]=kc;
}

// ---------- K5: pattern-gate P (pre-normalization) ----------
__global__ __launch_bounds__(256) void k_ppre(
  const float* __restrict__ vis, const float* __restrict__ scraw,
  const float* __restrict__ energy, const float* __restrict__ params,
  float* __restrict__ ppre)
{
  int w=threadIdx.x, h=blockIdx.x, b=blockIdx.y;
  int p=h*W_+w;
  const float* pr = params + b*32;
  size_t base = (size_t)b*NA*HW_ + p;
  float se[NA], sc[NA], vf[NA];
  #pragma unroll
  for (int n=0;n<NA;++n){
    float vv = vis[base + (size_t)n*HW_];
    float f = (vv>0.f)?1.f:0.f; vf[n]=f;
    se[n] = clip01((energy[base+(size_t)n*HW_]-pr[n])/(pr[5+n]-pr[n]+EPS_))*f;
    sc[n] = clip01((scraw[base+(size_t)n*HW_]-pr[10+n])/(pr[15+n]-pr[10+n]+EPS_))*f;
  }
  float sup = 0.f;
  #pragma unroll
  for (int n=1;n<NA;++n) sup += (0.8f*se[n]+0.2f*sc[n])*vf[n];
  sup *= 0.25f;
  float de = clip01(((1.f-se[0])-pr[20])/(pr[21]-pr[20]+EPS_))*vf[0];
  float dc = clip01(((1.f-sc[0])-pr[22])/(pr[23]-pr[22]+EPS_))*vf[0];
  float D  = (0.7f*de + 0.3f*dc)*vf[0];
  bool ke = (se[0] <= pr[24]) && (vf[0]>0.f);
  bool kc = (sc[0] <= pr[25]) && (vf[0]>0.f);
  float kem = (ke&&kc)?1.f:0.f;
  ppre[(size_t)b*HW_+p] = D*sup*(1.f-kem);
}

// ---------- K6: winner argmax + owner/comm bits ----------
__global__ __launch_bounds__(256) void k_owner(
  const float* __restrict__ vis, const float* __restrict__ scraw,
  const float* __restrict__ sfull, const float* __restrict__ ppre,
  const float* __restrict__ statsP, int* __restrict__ omask)
{
  int w=threadIdx.x,h=blockIdx.x,b=blockIdx.y;
  int p=h*W_+w;
  const float* sP = statsP + b*16;
  int cntP=(int)sP[0];
  float plo = quantv(cntP,0.2f,sP[1],sP[2]);
  float phi = quantv(cntP,0.8f,sP[3],sP[4]);
  size_t base=(size_t)b*NA*HW_+p;
  float vf0 = (vis[base]>0.f)?1.f:0.f;
  float Pf = clip01((ppre[(size_t)b*HW_+p]-plo)/(phi-plo+EPS_))*vf0;
  float gate = 0.1f + 0.9f*Pf;
  int winner=0; float best=-1.f;
  int cbits=0;
  #pragma unroll
  for (int n=0;n<NA;++n){
    float vv = vis[base+(size_t)n*HW_];
    float f=(vv>0.f)?1.f:0.f;
    float s = ((sfull[base+(size_t)n*HW_]*f)*gate)*f;
    if (s>best){best=s;winner=n;}
    bool cm = (n==0) || (scraw[base+(size_t)n*HW_] > 0.5f);
    if (cm) cbits |= 1<<n;
  }
  int ob = ((cbits>>winner)&1) ? (1<<winner) : 0;
  omask[(size_t)b*HW_+p] = ob | (cbits<<8);
}

// ---------- K7: 3x3 dilation, final mask, effective-rate count ----------
__global__ __launch_bounds__(256) void k_final(
  const int* __restrict__ omask, int* __restrict__ fmask, int* __restrict__ counter)
{
  int w=threadIdx.x,h=blockIdx.x,b=blockIdx.y;
  int p=h*W_+w;
  const int* om = omask + (size_t)b*HW_;
  int ow=0;
  #pragma unroll
  for (int dy=-1;dy<=1;++dy){
    int y=h+dy; if (y<0||y>=H_) continue;
    #pragma unroll
    for (int dx=-1;dx<=1;++dx){
      int x=w+dx; if (x<0||x>=W_) continue;
      ow |= om[y*W_+x];
    }
  }
  int cbits=(om[p]>>8)&31;
  int fin = ow & cbits & 31;
  fmask[(size_t)b*HW_+p]=fin;
  int cn = __popc(fin & 30);
  for (int off=32;off;off>>=1) cn += __shfl_down(cn,off);
  if ((threadIdx.x&63)==0) atomicAdd(counter, cn);
}

// ---------- K8: masked-max warped output via quad-tap loads ----------
// Per agent the two x-taps are cx0,cx0+1: one aligned dwordx4 at (cx0&~3) covers
// both 75% of the time; scalar fallback (exec-masked) for the (cx0&3)==3 lanes.
__global__ __launch_bounds__(256, 2) void k_out(
  const float* __restrict__ x, const float* __restrict__ nam,
  const int* __restrict__ fmask, const int* __restrict__ counter,
  float* __restrict__ out, int out_size)
{
  int w=threadIdx.x, h=blockIdx.x, b=blockIdx.y;
  int p=h*W_+w;
  int fin = fmask[(size_t)b*HW_+p] & 31;
  float init = (__popc(fin)<NA) ? 0.f : -__builtin_inff();
  int oq0[NA], oq1[NA], li0[NA], li1[NA], os0[NA], os1[NA];
  bool sep[NA];
  float wa[NA],wb[NA],wc[NA],wd[NA];
  #pragma unroll
  for (int n=0;n<NA;++n){
    Taps t = make_taps(nam + (size_t)(b*NA*NA+n)*6, h, w);
    int cx0 = t.o00 & (W_-1);
    int cx1 = t.o01 & (W_-1);
    int r0  = t.o00 - cx0;          // cy0*W
    int r1  = t.o10 - cx0;          // cy1*W
    int q   = cx0 & ~3;
    oq0[n] = r0 + q; oq1[n] = r1 + q;
    li0[n] = cx0 & 3;
    int l1 = cx1 - q;
    sep[n] = (l1 > 3);
    li1[n] = sep[n] ? 0 : l1;
    os0[n] = r0 + cx1; os1[n] = r1 + cx1;
    wa[n]=t.w00; wb[n]=t.w01; wc[n]=t.w10; wd[n]=t.w11;
  }
  #pragma unroll 1
  for (int cb=0; cb<NC/8; ++cb){
    float m[8];
    #pragma unroll
    for (int c=0;c<8;++c) m[c]=init;
    #pragma unroll
    for (int n=0;n<NA;++n){
      if (!((fin>>n)&1)) continue;
      const float* pc = x + ((size_t)(b*NA+n)*NC + cb*8)*HW_;
      float4 Q0[8], Q1[8];
      float  S0[8]={0,0,0,0,0,0,0,0}, S1[8]={0,0,0,0,0,0,0,0};
      {
        const float* pp = pc;
        #pragma unroll
        for (int c=0;c<8;++c){
          Q0[c] = *reinterpret_cast<const float4*>(pp + oq0[n]);
          Q1[c] = *reinterpret_cast<const float4*>(pp + oq1[n]);
          pp += HW_;
        }
      }
      if (sep[n]){
        const float* ps = pc;
        #pragma unroll
        for (int c=0;c<8;++c){ S0[c]=ps[os0[n]]; S1[c]=ps[os1[n]]; ps += HW_; }
      }
      #pragma unroll
      for (int c=0;c<8;++c){
        float v00 = sel4(Q0[c], li0[n]);
        float v10 = sel4(Q1[c], li0[n]);
        float v01 = sep[n] ? S0[c] : sel4(Q0[c], li1[n]);
        float v11 = sep[n] ? S1[c] : sel4(Q1[c], li1[n]);
        m[c] = fmaxf(m[c], wa[n]*v00 + wb[n]*v01 + wc[n]*v10 + wd[n]*v11);
      }
    }
    #pragma unroll
    for (int c=0;c<8;++c)
      out[(((size_t)b*NC + cb*8 + c)*H_+h)*W_+w] = m[c];
  }
  if (b==0 && h==0 && w==0)
    out[out_size-1] = (float)(*counter) * (1.0f/524288.0f);  // /(B*(N-1)*H*W)
}

extern "C" void kernel_launch(void* const* d_in, const int* in_sizes, int n_in,
                              void* d_out, int out_size, void* d_ws, size_t ws_size,
                              hipStream_t stream) {
  (void)in_sizes; (void)n_in;
  const float* x   = (const float*)d_in[0];
  const float* psm = (const float*)d_in[1];
  const float* nam = (const float*)d_in[3];
  float* out = (float*)d_out;

  float* ws     = (float*)d_ws;
  float* vis    = ws;                         // 20*HW
  float* scraw  = vis    + (size_t)NIMG*HW_;  // 20*HW
  float* sfull  = scraw  + (size_t)NIMG*HW_;  // 20*HW
  float* energy = sfull  + (size_t)NIMG*HW_;  // 20*HW
  float* ppre   = energy + (size_t)NIMG*HW_;  // 4*HW
  float* statsE = ppre   + (size_t)NB*HW_;    // 20*16
  float* statsC = statsE + NIMG*16;           // 20*16
  float* statsP = statsC + NIMG*16;           // 4*16
  float* params = statsP + NB*16;             // 4*32
  int*   omask  = (int*)(params + NB*32);     // 4*HW
  int*   fmask  = omask + (size_t)NB*HW_;     // 4*HW
  int*   counter= fmask + (size_t)NB*HW_;     // 1
  float* gram   = (float*)(counter + 64);     // 20*HW*8 (interleaved records)
  size_t need = (size_t)((gram + ((size_t)NIMG*HW_<<3)) - ws) * sizeof(float);

  hipLaunchKernelGGL(k_init, dim3(1), dim3(64), 0, stream, counter);
  if (ws_size >= need){
    hipLaunchKernelGGL(k_gram, dim3(NIMG*H_), dim3(64), 0, stream, x, gram);
    hipLaunchKernelGGL(k_warp2, dim3(H_,NIMG), dim3(W_), 0, stream,
                       psm, nam, gram, vis, scraw, sfull, energy);
  } else {
    hipLaunchKernelGGL(k_warp_stats_mono, dim3(W_/TWm, H_/THm, NIMG), dim3(256), 0, stream,
                       x, psm, nam, vis, scraw, sfull, energy);
  }
  hipLaunchKernelGGL(k_select, dim3(192), dim3(OS_T), 0, stream,
                     energy, scraw, ppre, vis, statsE, statsC, statsP, 0);
  hipLaunchKernelGGL(k_params, dim3(1), dim3(64), 0, stream, statsE, statsC, params);
  hipLaunchKernelGGL(k_ppre, dim3(H_,NB), dim3(W_), 0, stream,
                     vis, scraw, energy, params, ppre);
  hipLaunchKernelGGL(k_select, dim3(16), dim3(OS_T), 0, stream,
                     energy, scraw, ppre, vis, statsE, statsC, statsP, 1);
  hipLaunchKernelGGL(k_owner, dim3(H_,NB), dim3(W_), 0, stream,
                     vis, scraw, sfull, ppre, statsP, omask);
  hipLaunchKernelGGL(k_final, dim3(H_,NB), dim3(W_), 0, stream, omask, fmask, counter);
  hipLaunchKernelGGL(k_out, dim3(H_,NB), dim3(W_), 0, stream,
                     x, nam, fmask, counter, out, out_size);
}

// Round 12
// 199.867 us; speedup vs baseline: 1.3005x; 1.3005x over previous
//
#include <hip/hip_runtime.h>

#define W_    256
#define H_    128
#define HW_   32768
#define NB    4
#define NA    5
#define NC    64
#define NIMG  20
#define EPS_  1e-6f

// ---------- bilinear warp taps (matches reference affine_grid + grid_sample) ----------
struct Taps { int o00,o01,o10,o11; float w00,w01,w10,w11; };

__device__ inline void proj_pt(float M0,float M1,float M2,float M3,float M4,float M5,
                               int h,int w,float&px,float&py){
  float gx = 2.0f*((float)w+0.5f)/(float)W_ - 1.0f;
  float gy = 2.0f*((float)h+0.5f)/(float)H_ - 1.0f;
  float X = M0*gx + M1*gy + M2;
  float Y = M3*gx + M4*gy + M5;
  px = ((X+1.0f)*(float)W_ - 1.0f)*0.5f;
  py = ((Y+1.0f)*(float)H_ - 1.0f)*0.5f;
}

__device__ inline Taps make_taps(const float* __restrict__ M, int h, int w){
  float px,py; proj_pt(M[0],M[1],M[2],M[3],M[4],M[5],h,w,px,py);
  float x0f=floorf(px), y0f=floorf(py);
  float wx1=px-x0f, wx0=1.f-wx1, wy1=py-y0f, wy0=1.f-wy1;
  int x0=(int)x0f, y0=(int)y0f, x1=x0+1, y1=y0+1;
  bool vx0=(x0>=0)&&(x0<W_), vx1=(x1>=0)&&(x1<W_);
  bool vy0=(y0>=0)&&(y0<H_), vy1=(y1>=0)&&(y1<H_);
  int cx0=min(max(x0,0),W_-1), cx1=min(max(x1,0),W_-1);
  int cy0=min(max(y0,0),H_-1), cy1=min(max(y1,0),H_-1);
  Taps t;
  t.o00=cy0*W_+cx0; t.o01=cy0*W_+cx1; t.o10=cy1*W_+cx0; t.o11=cy1*W_+cx1;
  t.w00=(vy0&&vx0)?(wy0*wx0):0.f;
  t.w01=(vy0&&vx1)?(wy0*wx1):0.f;
  t.w10=(vy1&&vx0)?(wy1*wx0):0.f;
  t.w11=(vy1&&vx1)?(wy1*wx1):0.f;
  return t;
}

__device__ inline float clip01(float v){ return fminf(fmaxf(v,0.f),1.f); }
__device__ inline float sigmoidf_(float v){
  if (v>=0.f){ float e=expf(-v); return 1.f/(1.f+e); }
  float e=expf(v); return e/(1.f+e);
}
__device__ inline float quantv(int cnt, float q, float vlo, float vhi){
  if (cnt<=0) return 0.f;
  float pos = q*(float)(cnt-1);
  float frac = pos - floorf(pos);
  return vlo + frac*(vhi-vlo);
}
__device__ inline float ge_f(float t, float lo, float hi){
  return clip01((t-lo)/(hi-lo+EPS_));
}

#define SBAR __builtin_amdgcn_sched_barrier(0)

// ---------- K0: zero the effective-rate counter ----------
__global__ void k_init(int* counters){ if (threadIdx.x==0) counters[0] = 0; }

// ---------- K1a: source-domain Gram maps, interleaved 32B records ----------
// 1 wave per image row; XCD-swizzled (bijective, 2560%8==0); unroll 8 for MLP.
__global__ __launch_bounds__(64) void k_gram(
  const float* __restrict__ x, float* __restrict__ gram)
{
  int lane = threadIdx.x;
  int bx = blockIdx.x;              // 0..2559
  int lin = (bx&7)*(NIMG*H_/8) + (bx>>3);
  int bn = lin >> 7;
  int r  = lin & 127;
  int rn = min(r+1, H_-1);          // clamped next row (coeff-dead at r=127, finite)
  int col = lane<<2;
  const float* xb = x + (size_t)bn*NC*HW_;
  float4 aA={0,0,0,0}, aBx={0,0,0,0}, aBy={0,0,0,0}, aBd1={0,0,0,0}, aBd2={0,0,0,0};
  #pragma unroll 8
  for (int c=0;c<NC;++c){
    const float* pc = xb + (size_t)c*HW_;
    float4 a = *reinterpret_cast<const float4*>(pc + r*W_  + col);
    float4 b = *reinterpret_cast<const float4*>(pc + rn*W_ + col);
    float axn = __shfl(a.x, lane+1, 64);   // lane63 wraps: finite, coeff-dead (col 255)
    float bxn = __shfl(b.x, lane+1, 64);
    aA.x  = fmaf(a.x,a.x,aA.x);  aA.y  = fmaf(a.y,a.y,aA.y);
    aA.z  = fmaf(a.z,a.z,aA.z);  aA.w  = fmaf(a.w,a.w,aA.w);
    aBx.x = fmaf(a.x,a.y,aBx.x); aBx.y = fmaf(a.y,a.z,aBx.y);
    aBx.z = fmaf(a.z,a.w,aBx.z); aBx.w = fmaf(a.w,axn,aBx.w);
    aBy.x = fmaf(a.x,b.x,aBy.x); aBy.y = fmaf(a.y,b.y,aBy.y);
    aBy.z = fmaf(a.z,b.z,aBy.z); aBy.w = fmaf(a.w,b.w,aBy.w);
    aBd1.x= fmaf(a.x,b.y,aBd1.x);aBd1.y= fmaf(a.y,b.z,aBd1.y);
    aBd1.z= fmaf(a.z,b.w,aBd1.z);aBd1.w= fmaf(a.w,bxn,aBd1.w);
    aBd2.x= fmaf(a.y,b.x,aBd2.x);aBd2.y= fmaf(a.z,b.y,aBd2.y);
    aBd2.z= fmaf(a.w,b.z,aBd2.z);aBd2.w= fmaf(axn,b.w,aBd2.w);
  }
  float* g0 = gram + (((size_t)bn*HW_ + (size_t)r*W_ + col)<<3);
  float4 lo,hi;
  lo.x=aA.x; lo.y=aBx.x; lo.z=aBy.x; lo.w=aBd1.x; hi.x=aBd2.x; hi.y=0; hi.z=0; hi.w=0;
  *reinterpret_cast<float4*>(g0+ 0)=lo; *reinterpret_cast<float4*>(g0+ 4)=hi;
  lo.x=aA.y; lo.y=aBx.y; lo.z=aBy.y; lo.w=aBd1.y; hi.x=aBd2.y;
  *reinterpret_cast<float4*>(g0+ 8)=lo; *reinterpret_cast<float4*>(g0+12)=hi;
  lo.x=aA.z; lo.y=aBx.z; lo.z=aBy.z; lo.w=aBd1.z; hi.x=aBd2.z;
  *reinterpret_cast<float4*>(g0+16)=lo; *reinterpret_cast<float4*>(g0+20)=hi;
  lo.x=aA.w; lo.y=aBx.w; lo.z=aBy.w; lo.w=aBd1.w; hi.x=aBd2.w;
  *reinterpret_cast<float4*>(g0+24)=lo; *reinterpret_cast<float4*>(g0+28)=hi;
}

// ---------- K1b: warp + stats from Gram records ----------
__global__ __launch_bounds__(256) void k_warp2(
  const float* __restrict__ psm, const float* __restrict__ nam,
  const float* __restrict__ gram,
  float* __restrict__ vis, float* __restrict__ scraw, float* __restrict__ sfull,
  float* __restrict__ energy)
{
  int w = threadIdx.x, h = blockIdx.x, bn = blockIdx.y;
  int b = bn/NA, n = bn - b*NA;
  const float* M = nam + (size_t)(b*NA*NA + n)*6;
  float px,py; proj_pt(M[0],M[1],M[2],M[3],M[4],M[5],h,w,px,py);
  float x0f=floorf(px), y0f=floorf(py);
  float wx1=px-x0f, wx0=1.f-wx1, wy1=py-y0f, wy0=1.f-wy1;
  int x0=(int)x0f, y0=(int)y0f, x1=x0+1, y1=y0+1;
  bool vx0=(x0>=0)&&(x0<W_), vx1=(x1>=0)&&(x1<W_);
  bool vy0=(y0>=0)&&(y0<H_), vy1=(y1>=0)&&(y1<H_);
  int cx0=min(max(x0,0),W_-1), cx1=min(max(x1,0),W_-1);
  int cy0=min(max(y0,0),H_-1), cy1=min(max(y1,0),H_-1);
  float w00=(vy0&&vx0)?(wy0*wx0):0.f;
  float w01=(vy0&&vx1)?(wy0*wx1):0.f;
  float w10=(vy1&&vx0)?(wy1*wx0):0.f;
  float w11=(vy1&&vx1)?(wy1*wx1):0.f;
  int i00=cy0*W_+cx0, i01=cy0*W_+cx1, i10=cy1*W_+cx0, i11=cy1*W_+cx1;
  float vv = w00+w01+w10+w11;

  const float* p0 = psm + ((size_t)bn*2+0)*HW_;
  const float* p1 = psm + ((size_t)bn*2+1)*HW_;
  float c0 = w00*p0[i00]+w01*p0[i01]+w10*p0[i10]+w11*p0[i11];
  float c1 = w00*p1[i00]+w01*p1[i01]+w10*p1[i10]+w11*p1[i11];

  const float* G = gram + ((size_t)bn*HW_<<3);
  float4 R00 = *reinterpret_cast<const float4*>(G + ((size_t)i00<<3)); // A,Bx,By,D1
  float  D2  = G[((size_t)i00<<3)+4];
  float4 R01 = *reinterpret_cast<const float4*>(G + ((size_t)i01<<3));
  float4 R10 = *reinterpret_cast<const float4*>(G + ((size_t)i10<<3));
  float  A11 = G[(size_t)i11<<3];
  float e = w00*w00*R00.x + w01*w01*R01.x + w10*w10*R10.x + w11*w11*A11
          + 2.0f*( w00*w01*R00.y + w10*w11*R10.y
                 + w00*w10*R00.z + w01*w11*R01.z
                 + w00*w11*R00.w + w01*w10*D2 );

  size_t idx = (size_t)bn*HW_ + (size_t)h*W_ + w;
  vis[idx]=vv;
  scraw[idx]=fmaxf(sigmoidf_(c0), sigmoidf_(c1));
  sfull[idx]=(clip01(c0)+clip01(c1))*0.5f;
  energy[idx]=e*(1.0f/64.0f);
}

// ---------- K1-mono (fallback if ws too small): R7 proven kernel ----------
#define TWm    32
#define THm    16
#define CAPm   2048
#define TRIPSm 2
#define NBUFm  3
__global__ __launch_bounds__(256) void k_warp_stats_mono(
  const float* __restrict__ x, const float* __restrict__ psm, const float* __restrict__ nam,
  float* __restrict__ vis, float* __restrict__ scraw, float* __restrict__ sfull,
  float* __restrict__ energy)
{
  __shared__ __align__(16) float smem[NBUFm][CAPm];
  int tid = threadIdx.x;
  int tx = blockIdx.x, ty = blockIdx.y, bn = blockIdx.z;
  int b = bn/NA, n = bn - b*NA;
  const float* M = nam + (size_t)(b*NA*NA + n)*6;
  float M0=M[0],M1=M[1],M2=M[2],M3=M[3],M4=M[4],M5=M[5];
  int tw0 = tx*TWm, th0 = ty*THm;
  int r  = tid>>4;
  int cb = (tid&15)<<1;
  int h  = th0 + r;
  int w0 = tw0 + cb;
  float pxa,pya,pxb,pyb,pxc,pyc,pxd,pyd;
  proj_pt(M0,M1,M2,M3,M4,M5, th0,       tw0,       pxa,pya);
  proj_pt(M0,M1,M2,M3,M4,M5, th0,       tw0+TWm-1, pxb,pyb);
  proj_pt(M0,M1,M2,M3,M4,M5, th0+THm-1, tw0,       pxc,pyc);
  proj_pt(M0,M1,M2,M3,M4,M5, th0+THm-1, tw0+TWm-1, pxd,pyd);
  float pxmin=fminf(fminf(pxa,pxb),fminf(pxc,pxd));
  float pxmax=fmaxf(fmaxf(pxa,pxb),fmaxf(pxc,pxd));
  float pymin=fminf(fminf(pya,pyb),fminf(pyc,pyd));
  float pymax=fmaxf(fmaxf(pya,pyb),fmaxf(pyc,pyd));
  int xs = min(max((int)floorf(pxmin)-1, 0), W_-1);
  int xe = min(max((int)floorf(pxmax)+2, 0), W_-1);
  int ys = min(max((int)floorf(pymin)-1, 0), H_-1);
  int ye = min(max((int)floorf(pymax)+2, 0), H_-1);
  int xs4 = xs & ~3;
  int bwid = xe - xs4 + 1, bh = ye - ys + 1;
  int nck = (bwid+3)>>2;
  int bwp = nck<<2;
  int E2 = bh*bwp;
  bool ok = (E2 <= CAPm);
  float vvv[2], w00_[2],w01_[2],w10_[2],w11_[2];
  int   gx0[2],gx1[2],gy0c[2],gy1c[2];
  int   rx0[2]; bool vx0f[2];
  #pragma unroll
  for (int k=0;k<2;++k){
    float px,py; proj_pt(M0,M1,M2,M3,M4,M5, h, w0+k, px,py);
    float x0f=floorf(px), y0f=floorf(py);
    float wx1=px-x0f, wx0=1.f-wx1, wy1=py-y0f, wy0=1.f-wy1;
    int x0=(int)x0f, y0=(int)y0f, x1=x0+1, y1=y0+1;
    bool vx0=(x0>=0)&&(x0<W_), vx1=(x1>=0)&&(x1<W_);
    bool vy0=(y0>=0)&&(y0<H_), vy1=(y1>=0)&&(y1<H_);
    float w00=(vy0&&vx0)?(wy0*wx0):0.f;
    float w01=(vy0&&vx1)?(wy0*wx1):0.f;
    float w10=(vy1&&vx0)?(wy1*wx0):0.f;
    float w11=(vy1&&vx1)?(wy1*wx1):0.f;
    w00_[k]=w00; w01_[k]=w01; w10_[k]=w10; w11_[k]=w11;
    vvv[k]=w00+w01+w10+w11;
    gx0[k]=min(max(x0,0),W_-1); gx1[k]=min(max(x1,0),W_-1);
    gy0c[k]=min(max(y0,0),H_-1); gy1c[k]=min(max(y1,0),H_-1);
    rx0[k]=x0; vx0f[k]=vx0;
  }
  size_t idx = (size_t)bn*HW_ + (size_t)h*W_ + w0;
  float acc[2] = {0.f,0.f};
  int srcoff[TRIPSm]; int ldsbase = (tid>>6)<<6;
  const float* xb0 = x + (size_t)bn*NC*HW_ + (size_t)ys*W_ + xs4;
  if (ok){
    int totq = bh*nck;
    unsigned magic = (unsigned)((0x100000000ULL + (unsigned)nck - 1) / (unsigned)nck);
    int colcap = (W_-4) - xs4;
    #pragma unroll
    for (int k=0;k<TRIPSm;++k){
      int qq = min(tid + (k<<8), totq-1);
      int row = (int)__umulhi((unsigned)qq, magic);
      int col = (qq - row*nck)<<2;
      srcoff[k] = row*W_ + min(col, colcap);
    }
  }
  auto issue = [&](int ch, int bsel){
    const float* src = xb0 + (size_t)ch*HW_;
    #pragma unroll
    for (int k=0;k<TRIPSm;++k){
      __builtin_amdgcn_global_load_lds(
        (const __attribute__((address_space(1))) void*)(src + srcoff[k]),
        (__attribute__((address_space(3))) void*)&smem[bsel][(ldsbase + (k<<8))<<2],
        16, 0, 0);
    }
  };
  if (ok){ issue(0,0); issue(1,1); }
  {
    const float* p0 = psm + ((size_t)bn*2+0)*HW_;
    const float* p1 = psm + ((size_t)bn*2+1)*HW_;
    #pragma unroll
    for (int k=0;k<2;++k){
      int o00=gy0c[k]*W_+gx0[k], o01=gy0c[k]*W_+gx1[k];
      int o10=gy1c[k]*W_+gx0[k], o11=gy1c[k]*W_+gx1[k];
      float c0 = w00_[k]*p0[o00]+w01_[k]*p0[o01]+w10_[k]*p0[o10]+w11_[k]*p0[o11];
      float c1 = w00_[k]*p1[o00]+w01_[k]*p1[o01]+w10_[k]*p1[o10]+w11_[k]*p1[o11];
      vis[idx+k]   = vvv[k];
      scraw[idx+k] = fmaxf(sigmoidf_(c0), sigmoidf_(c1));
      sfull[idx+k] = (clip01(c0)+clip01(c1))*0.5f;
    }
  }
  if (ok){
    int a0[2],a1[2]; float e0[2],e1[2],f0[2],f1[2];
    #pragma unroll
    for (int k=0;k<2;++k){
      int bc = min(max(rx0[k]-xs4,0), bwp-1);
      a0[k] = (gy0c[k]-ys)*bwp + bc;
      a1[k] = (gy1c[k]-ys)*bwp + bc;
      bool v0 = vx0f[k];
      e0[k] = v0 ? w00_[k] : w01_[k];
      e1[k] = v0 ? w01_[k] : 0.f;
      f0[k] = v0 ? w10_[k] : w11_[k];
      f1[k] = v0 ? w11_[k] : 0.f;
    }
    #pragma unroll 1
    for (int c=0;c<NC;++c){
      asm volatile("s_waitcnt vmcnt(2)" ::: "memory"); SBAR;
      __builtin_amdgcn_s_barrier(); SBAR;
      {
        int nc2 = c+2 < NC ? c+2 : NC-1;
        issue(nc2, (c+2)%NBUFm);
      }
      const float* B = smem[c%NBUFm];
      #pragma unroll
      for (int k=0;k<2;++k){
        float r00=B[a0[k]], r01=B[a0[k]+1];
        float r10=B[a1[k]], r11=B[a1[k]+1];
        float v = e0[k]*r00 + e1[k]*r01 + f0[k]*r10 + f1[k]*r11;
        acc[k] += v*v;
      }
    }
    asm volatile("s_waitcnt vmcnt(0)" ::: "memory");
  } else {
    const float* xb = x + (size_t)bn*NC*HW_;
    int go00[2],go01[2],go10[2],go11[2];
    #pragma unroll
    for (int k=0;k<2;++k){
      go00[k]=gy0c[k]*W_+gx0[k]; go01[k]=gy0c[k]*W_+gx1[k];
      go10[k]=gy1c[k]*W_+gx0[k]; go11[k]=gy1c[k]*W_+gx1[k];
    }
    for (int c=0;c<NC;++c){
      const float* pc = xb + (size_t)c*HW_;
      #pragma unroll
      for (int k=0;k<2;++k){
        float v = w00_[k]*pc[go00[k]] + w01_[k]*pc[go01[k]]
                + w10_[k]*pc[go10[k]] + w11_[k]*pc[go11[k]];
        acc[k] += v*v;
      }
    }
  }
  #pragma unroll
  for (int k=0;k<2;++k) energy[idx+k] = acc[k]*(1.0f/64.0f);
}

// ---------- K3: radix-select, ONE BLOCK PER (image, rank); count computed in-block ----------
#define OS_T 1024
__global__ __launch_bounds__(1024) void k_select(
    const float* __restrict__ energy, const float* __restrict__ scraw,
    const float* __restrict__ ppre, const float* __restrict__ vis,
    float* __restrict__ statsE, float* __restrict__ statsC, float* __restrict__ statsP,
    int mode)
{
  __shared__ int hist[16*256];
  __shared__ int cum[256];
  __shared__ unsigned s_pre;
  __shared__ int s_rk;
  __shared__ int s_cnt;
  int tid = threadIdx.x;
  int t = blockIdx.x;

  const float* d; const float* m; float* stats; int img, r;
  if (mode==0){
    bool isC = (t>=96); int tt = isC ? t-96 : t;
    if (tt<80){ img=tt>>2; r=tt&3; } else { int j=tt-80; img=(j>>2)*NA; r=4+(j&3); }
    d = (isC?scraw:energy) + (size_t)img*HW_;
    m = vis + (size_t)img*HW_;
    stats = isC?statsC:statsE;
  } else {
    img = t>>2; r = t&3;
    d = ppre + (size_t)img*HW_;
    m = vis + (size_t)(img*NA)*HW_;
    stats = statsP;
  }

  if (tid==0) s_cnt = 0;
  __syncthreads();

  unsigned key[32];
  int cc = 0;
  #pragma unroll
  for (int k=0;k<32;++k){
    int i = tid + (k<<10);
    unsigned u = __float_as_uint(d[i]);
    unsigned kk = (u & 0x80000000u) ? ~u : (u|0x80000000u);
    bool valid = (m[i] > 0.f);
    key[k] = valid ? kk : 0xFFFFFFFFu;
    cc += valid ? 1 : 0;
  }
  #pragma unroll
  for (int off=32;off;off>>=1) cc += __shfl_down(cc,off);
  if ((tid&63)==0) atomicAdd(&s_cnt, cc);
  __syncthreads();
  int cnt = s_cnt;
  int cm1 = cnt>0 ? cnt-1 : 0;
  float p2 = 0.2f*(float)cm1, p8 = 0.8f*(float)cm1;
  int l2=(int)floorf(p2), h2=(int)ceilf(p2), l8=(int)floorf(p8), h8=(int)ceilf(p8);
  int rank;
  switch(r){
    case 0: rank=l2; break;      case 1: rank=h2; break;
    case 2: rank=l8; break;      case 3: rank=h8; break;
    case 4: rank=cm1-l2; break;  case 5: rank=cm1-h2; break;
    case 6: rank=cm1-l8; break;  default: rank=cm1-h8; break;
  }
  if (tid==0){ s_pre=0u; s_rk=rank; }
  int slice = tid & 15;
  #pragma unroll
  for (int round=0; round<4; ++round){
    const int shift = 24 - 8*round;
    for (int i=tid;i<16*256;i+=OS_T) hist[i]=0;
    __syncthreads();
    unsigned pre = s_pre;
    if (round==0){
      #pragma unroll
      for (int k=0;k<32;++k)
        atomicAdd(&hist[slice*256 + (key[k]>>24)], 1);
    } else {
      #pragma unroll
      for (int k=0;k<32;++k)
        if ((key[k]>>(shift+8)) == pre)
          atomicAdd(&hist[slice*256 + ((key[k]>>shift)&255u)], 1);
    }
    __syncthreads();
    if (tid<256){
      int tt2=0;
      #pragma unroll
      for (int s=0;s<16;++s) tt2 += hist[s*256+tid];
      cum[tid]=tt2;
    }
    __syncthreads();
    if (tid<64){
      int c0=cum[4*tid+0],c1=cum[4*tid+1],c2=cum[4*tid+2],c3=cum[4*tid+3];
      int i0=c0, i1=i0+c1, i2=i1+c2, i3=i2+c3;
      int tot=i3, scan=tot;
      #pragma unroll
      for (int off=1;off<64;off<<=1){ int v=__shfl_up(scan,off); if (tid>=off) scan+=v; }
      int base = scan-tot;
      int rk = s_rk; unsigned pr = s_pre;
      int b0=base, b1=base+i0, b2=base+i1, b3=base+i2, e3=base+i3;
      if      (rk>=b0 && rk<b1){ s_pre=(pr<<8)|(unsigned)(4*tid+0); s_rk=rk-b0; }
      else if (rk>=b1 && rk<b2){ s_pre=(pr<<8)|(unsigned)(4*tid+1); s_rk=rk-b1; }
      else if (rk>=b2 && rk<b3){ s_pre=(pr<<8)|(unsigned)(4*tid+2); s_rk=rk-b2; }
      else if (rk>=b3 && rk<e3){ s_pre=(pr<<8)|(unsigned)(4*tid+3); s_rk=rk-b3; }
    }
    __syncthreads();
  }
  if (tid==0){
    unsigned k = s_pre;
    unsigned u = (k & 0x80000000u) ? (k & 0x7FFFFFFFu) : ~k;
    stats[img*16 + 1 + r] = __uint_as_float(u);
    if (r==0) stats[img*16] = (float)cnt;
  }
}

// ---------- K4: per-batch scalar params from order stats ----------
__global__ void k_params(const float* __restrict__ statsE, const float* __restrict__ statsC,
                         float* __restrict__ params){
  int b = threadIdx.x;
  if (b>=NB) return;
  float* pr = params + b*32;
  for (int n=0;n<NA;++n){
    const float* sE = statsE + (size_t)(b*NA+n)*16;
    const float* sC = statsC + (size_t)(b*NA+n)*16;
    int cE=(int)sE[0], cC=(int)sC[0];
    pr[n]    = quantv(cE,0.2f,sE[1],sE[2]);
    pr[5+n]  = quantv(cE,0.8f,sE[3],sE[4]);
    pr[10+n] = quantv(cC,0.2f,sC[1],sC[2]);
    pr[15+n] = quantv(cC,0.8f,sC[3],sC[4]);
  }
  const float* sE0 = statsE + (size_t)(b*NA)*16;
  const float* sC0 = statsC + (size_t)(b*NA)*16;
  float loe=pr[0], hie=pr[5], loc=pr[10], hic=pr[15];
  float de_lo=0.f,de_hi=0.f,ke=0.f, dc_lo=0.f,dc_hi=0.f,kc=0.f;
  int c0=(int)sE0[0];
  if (c0>0){
    int cm1=c0-1;
    float pos2=0.2f*(float)cm1, pos8=0.8f*(float)cm1;
    float f2=pos2-floorf(pos2), f8=pos8-floorf(pos8);
    float a,bb;
    a=1.f-ge_f(sE0[5],loe,hie); bb=1.f-ge_f(sE0[6],loe,hie); de_lo=a+f2*(bb-a);
    a=1.f-ge_f(sE0[7],loe,hie); bb=1.f-ge_f(sE0[8],loe,hie); de_hi=a+f8*(bb-a);
    a=ge_f(sE0[1],loe,hie);     bb=ge_f(sE0[2],loe,hie);     ke  =a+f2*(bb-a);
  }
  int c0c=(int)sC0[0];
  if (c0c>0){
    int cm1=c0c-1;
    float pos2=0.2f*(float)cm1, pos8=0.8f*(float)cm1;
    float f2=pos2-floorf(pos2), f8=pos8-floorf(pos8);
    float a,bb;
    a=1.f-ge_f(sC0[5],loc,hic); bb=1.f-ge_f(sC0[6],loc,hic); dc_lo=a+f2*(bb-a);
    a=1.f-ge_f(sC0[7],loc,hic); bb=1.f-ge_f(sC0[8],loc,hic); dc_hi=a+f8*(bb-a);
    a=ge_f(sC0[1],loc,hic);     bb=ge_f(sC0[2],loc,hic);     kc  =a+f2*(bb-a);
  }
  pr[20]=de_lo; pr[21]=de_hi; pr[22]=dc_lo; pr[23]=dc_hi; pr[24]=ke; pr[25]=kc;
}

// ---------- K5: pattern-gate P (pre-normalization) ----------
__global__ __launch_bounds__(256) void k_ppre(
  const float* __restrict__ vis, const float* __restrict__ scraw,
  const float* __restrict__ energy, const float* __restrict__ params,
  float* __restrict__ ppre)
{
  int w=threadIdx.x, h=blockIdx.x, b=blockIdx.y;
  int p=h*W_+w;
  const float* pr = params + b*32;
  size_t base = (size_t)b*NA*HW_ + p;
  float se[NA], sc[NA], vf[NA];
  #pragma unroll
  for (int n=0;n<NA;++n){
    float vv = vis[base + (size_t)n*HW_];
    float f = (vv>0.f)?1.f:0.f; vf[n]=f;
    se[n] = clip01((energy[base+(size_t)n*HW_]-pr[n])/(pr[5+n]-pr[n]+EPS_))*f;
    sc[n] = clip01((scraw[base+(size_t)n*HW_]-pr[10+n])/(pr[15+n]-pr[10+n]+EPS_))*f;
  }
  float sup = 0.f;
  #pragma unroll
  for (int n=1;n<NA;++n) sup += (0.8f*se[n]+0.2f*sc[n])*vf[n];
  sup *= 0.25f;
  float de = clip01(((1.f-se[0])-pr[20])/(pr[21]-pr[20]+EPS_))*vf[0];
  float dc = clip01(((1.f-sc[0])-pr[22])/(pr[23]-pr[22]+EPS_))*vf[0];
  float D  = (0.7f*de + 0.3f*dc)*vf[0];
  bool ke = (se[0] <= pr[24]) && (vf[0]>0.f);
  bool kc = (sc[0] <= pr[25]) && (vf[0]>0.f);
  float kem = (ke&&kc)?1.f:0.f;
  ppre[(size_t)b*HW_+p] = D*sup*(1.f-kem);
}

// ---------- K6: winner argmax + owner/comm bits ----------
__global__ __launch_bounds__(256) void k_owner(
  const float* __restrict__ vis, const float* __restrict__ scraw,
  const float* __restrict__ sfull, const float* __restrict__ ppre,
  const float* __restrict__ statsP, int* __restrict__ omask)
{
  int w=threadIdx.x,h=blockIdx.x,b=blockIdx.y;
  int p=h*W_+w;
  const float* sP = statsP + b*16;
  int cntP=(int)sP[0];
  float plo = quantv(cntP,0.2f,sP[1],sP[2]);
  float phi = quantv(cntP,0.8f,sP[3],sP[4]);
  size_t base=(size_t)b*NA*HW_+p;
  float vf0 = (vis[base]>0.f)?1.f:0.f;
  float Pf = clip01((ppre[(size_t)b*HW_+p]-plo)/(phi-plo+EPS_))*vf0;
  float gate = 0.1f + 0.9f*Pf;
  int winner=0; float best=-1.f;
  int cbits=0;
  #pragma unroll
  for (int n=0;n<NA;++n){
    float vv = vis[base+(size_t)n*HW_];
    float f=(vv>0.f)?1.f:0.f;
    float s = ((sfull[base+(size_t)n*HW_]*f)*gate)*f;
    if (s>best){best=s;winner=n;}
    bool cm = (n==0) || (scraw[base+(size_t)n*HW_] > 0.5f);
    if (cm) cbits |= 1<<n;
  }
  int ob = ((cbits>>winner)&1) ? (1<<winner) : 0;
  omask[(size_t)b*HW_+p] = ob | (cbits<<8);
}

// ---------- K7: 3x3 dilation, final mask, effective-rate count ----------
__global__ __launch_bounds__(256) void k_final(
  const int* __restrict__ omask, int* __restrict__ fmask, int* __restrict__ counter)
{
  int w=threadIdx.x,h=blockIdx.x,b=blockIdx.y;
  int p=h*W_+w;
  const int* om = omask + (size_t)b*HW_;
  int ow=0;
  #pragma unroll
  for (int dy=-1;dy<=1;++dy){
    int y=h+dy; if (y<0||y>=H_) continue;
    #pragma unroll
    for (int dx=-1;dx<=1;++dx){
      int x=w+dx; if (x<0||x>=W_) continue;
      ow |= om[y*W_+x];
    }
  }
  int cbits=(om[p]>>8)&31;
  int fin = ow & cbits & 31;
  fmask[(size_t)b*HW_+p]=fin;
  int cn = __popc(fin & 30);
  for (int off=32;off;off>>=1) cn += __shfl_down(cn,off);
  if ((threadIdx.x&63)==0) atomicAdd(counter, cn);
}

// ---------- K8: masked-max warped output (R10 proven scalar-gather form) ----------
__global__ __launch_bounds__(256, 2) void k_out(
  const float* __restrict__ x, const float* __restrict__ nam,
  const int* __restrict__ fmask, const int* __restrict__ counter,
  float* __restrict__ out, int out_size)
{
  int w=threadIdx.x, h=blockIdx.x, b=blockIdx.y;
  int p=h*W_+w;
  int fin = fmask[(size_t)b*HW_+p] & 31;
  float init = (__popc(fin)<NA) ? 0.f : -__builtin_inff();
  Taps tp[NA];
  #pragma unroll
  for (int n=0;n<NA;++n) tp[n] = make_taps(nam + (size_t)(b*NA*NA+n)*6, h, w);
  #pragma unroll 1
  for (int cb=0; cb<NC/16; ++cb){
    float m[16];
    #pragma unroll
    for (int c=0;c<16;++c) m[c]=init;
    #pragma unroll
    for (int n=0;n<NA;++n){
      if (!((fin>>n)&1)) continue;
      const float* pc = x + ((size_t)(b*NA+n)*NC + cb*16)*HW_;
      float a00[16],a01[16],a10[16],a11[16];
      #pragma unroll
      for (int c=0;c<16;++c){
        a00[c]=pc[tp[n].o00]; a01[c]=pc[tp[n].o01]; a10[c]=pc[tp[n].o10]; a11[c]=pc[tp[n].o11];
        pc += HW_;
      }
      #pragma unroll
      for (int c=0;c<16;++c){
        float v = tp[n].w00*a00[c] + tp[n].w01*a01[c] + tp[n].w10*a10[c] + tp[n].w11*a11[c];
        m[c] = fmaxf(m[c], v);
      }
    }
    #pragma unroll
    for (int c=0;c<16;++c)
      out[(((size_t)b*NC + cb*16 + c)*H_+h)*W_+w] = m[c];
  }
  if (b==0 && h==0 && w==0)
    out[out_size-1] = (float)(*counter) * (1.0f/524288.0f);  // /(B*(N-1)*H*W)
}

extern "C" void kernel_launch(void* const* d_in, const int* in_sizes, int n_in,
                              void* d_out, int out_size, void* d_ws, size_t ws_size,
                              hipStream_t stream) {
  (void)in_sizes; (void)n_in;
  const float* x   = (const float*)d_in[0];
  const float* psm = (const float*)d_in[1];
  const float* nam = (const float*)d_in[3];
  float* out = (float*)d_out;

  float* ws     = (float*)d_ws;
  float* vis    = ws;                         // 20*HW
  float* scraw  = vis    + (size_t)NIMG*HW_;  // 20*HW
  float* sfull  = scraw  + (size_t)NIMG*HW_;  // 20*HW
  float* energy = sfull  + (size_t)NIMG*HW_;  // 20*HW
  float* ppre   = energy + (size_t)NIMG*HW_;  // 4*HW
  float* statsE = ppre   + (size_t)NB*HW_;    // 20*16
  float* statsC = statsE + NIMG*16;           // 20*16
  float* statsP = statsC + NIMG*16;           // 4*16
  float* params = statsP + NB*16;             // 4*32
  int*   omask  = (int*)(params + NB*32);     // 4*HW
  int*   fmask  = omask + (size_t)NB*HW_;     // 4*HW
  int*   counter= fmask + (size_t)NB*HW_;     // 1
  float* gram   = (float*)(counter + 64);     // 20*HW*8 (interleaved records)
  size_t need = (size_t)((gram + ((size_t)NIMG*HW_<<3)) - ws) * sizeof(float);

  hipLaunchKernelGGL(k_init, dim3(1), dim3(64), 0, stream, counter);
  if (ws_size >= need){
    hipLaunchKernelGGL(k_gram, dim3(NIMG*H_), dim3(64), 0, stream, x, gram);
    hipLaunchKernelGGL(k_warp2, dim3(H_,NIMG), dim3(W_), 0, stream,
                       psm, nam, gram, vis, scraw, sfull, energy);
  } else {
    hipLaunchKernelGGL(k_warp_stats_mono, dim3(W_/TWm, H_/THm, NIMG), dim3(256), 0, stream,
                       x, psm, nam, vis, scraw, sfull, energy);
  }
  hipLaunchKernelGGL(k_select, dim3(192), dim3(OS_T), 0, stream,
                     energy, scraw, ppre, vis, statsE, statsC, statsP, 0);
  hipLaunchKernelGGL(k_params, dim3(1), dim3(64), 0, stream, statsE, statsC, params);
  hipLaunchKernelGGL(k_ppre, dim3(H_,NB), dim3(W_), 0, stream,
                     vis, scraw, energy, params, ppre);
  hipLaunchKernelGGL(k_select, dim3(16), dim3(OS_T), 0, stream,
                     energy, scraw, ppre, vis, statsE, statsC, statsP, 1);
  hipLaunchKernelGGL(k_owner, dim3(H_,NB), dim3(W_), 0, stream,
                     vis, scraw, sfull, ppre, statsP, omask);
  hipLaunchKernelGGL(k_final, dim3(H_,NB), dim3(W_), 0, stream, omask, fmask, counter);
  hipLaunchKernelGGL(k_out, dim3(H_,NB), dim3(W_), 0, stream,
                     x, nam, fmask, counter, out, out_size);
}

// Round 14
// 199.793 us; speedup vs baseline: 1.3010x; 1.0004x over previous
//
#include <hip/hip_runtime.h>

#define W_    256
#define H_    128
#define HW_   32768
#define NB    4
#define NA    5
#define NC    64
#define NIMG  20
#define EPS_  1e-6f

// ---------- bilinear warp taps (matches reference affine_grid + grid_sample) ----------
struct Taps { int o00,o01,o10,o11; float w00,w01,w10,w11; };

__device__ inline void proj_pt(float M0,float M1,float M2,float M3,float M4,float M5,
                               int h,int w,float&px,float&py){
  float gx = 2.0f*((float)w+0.5f)/(float)W_ - 1.0f;
  float gy = 2.0f*((float)h+0.5f)/(float)H_ - 1.0f;
  float X = M0*gx + M1*gy + M2;
  float Y = M3*gx + M4*gy + M5;
  px = ((X+1.0f)*(float)W_ - 1.0f)*0.5f;
  py = ((Y+1.0f)*(float)H_ - 1.0f)*0.5f;
}

__device__ inline Taps make_taps(const float* __restrict__ M, int h, int w){
  float px,py; proj_pt(M[0],M[1],M[2],M[3],M[4],M[5],h,w,px,py);
  float x0f=floorf(px), y0f=floorf(py);
  float wx1=px-x0f, wx0=1.f-wx1, wy1=py-y0f, wy0=1.f-wy1;
  int x0=(int)x0f, y0=(int)y0f, x1=x0+1, y1=y0+1;
  bool vx0=(x0>=0)&&(x0<W_), vx1=(x1>=0)&&(x1<W_);
  bool vy0=(y0>=0)&&(y0<H_), vy1=(y1>=0)&&(y1<H_);
  int cx0=min(max(x0,0),W_-1), cx1=min(max(x1,0),W_-1);
  int cy0=min(max(y0,0),H_-1), cy1=min(max(y1,0),H_-1);
  Taps t;
  t.o00=cy0*W_+cx0; t.o01=cy0*W_+cx1; t.o10=cy1*W_+cx0; t.o11=cy1*W_+cx1;
  t.w00=(vy0&&vx0)?(wy0*wx0):0.f;
  t.w01=(vy0&&vx1)?(wy0*wx1):0.f;
  t.w10=(vy1&&vx0)?(wy1*wx0):0.f;
  t.w11=(vy1&&vx1)?(wy1*wx1):0.f;
  return t;
}

__device__ inline float clip01(float v){ return fminf(fmaxf(v,0.f),1.f); }
__device__ inline float sigmoidf_(float v){
  if (v>=0.f){ float e=expf(-v); return 1.f/(1.f+e); }
  float e=expf(v); return e/(1.f+e);
}
__device__ inline float quantv(int cnt, float q, float vlo, float vhi){
  if (cnt<=0) return 0.f;
  float pos = q*(float)(cnt-1);
  float frac = pos - floorf(pos);
  return vlo + frac*(vhi-vlo);
}
__device__ inline float ge_f(float t, float lo, float hi){
  return clip01((t-lo)/(hi-lo+EPS_));
}

#define SBAR __builtin_amdgcn_sched_barrier(0)

// ---------- K0: zero the effective-rate counter ----------
__global__ void k_init(int* counters){ if (threadIdx.x==0) counters[0] = 0; }

// ---------- K1a: source-domain Gram maps, interleaved 32B records ----------
// 1 wave per image row; XCD-swizzled (bijective, 2560%8==0); unroll 8 for MLP.
__global__ __launch_bounds__(64) void k_gram(
  const float* __restrict__ x, float* __restrict__ gram)
{
  int lane = threadIdx.x;
  int bx = blockIdx.x;              // 0..2559
  int lin = (bx&7)*(NIMG*H_/8) + (bx>>3);
  int bn = lin >> 7;
  int r  = lin & 127;
  int rn = min(r+1, H_-1);          // clamped next row (coeff-dead at r=127, finite)
  int col = lane<<2;
  const float* xb = x + (size_t)bn*NC*HW_;
  float4 aA={0,0,0,0}, aBx={0,0,0,0}, aBy={0,0,0,0}, aBd1={0,0,0,0}, aBd2={0,0,0,0};
  #pragma unroll 8
  for (int c=0;c<NC;++c){
    const float* pc = xb + (size_t)c*HW_;
    float4 a = *reinterpret_cast<const float4*>(pc + r*W_  + col);
    float4 b = *reinterpret_cast<const float4*>(pc + rn*W_ + col);
    float axn = __shfl(a.x, lane+1, 64);   // lane63 wraps: finite, coeff-dead (col 255)
    float bxn = __shfl(b.x, lane+1, 64);
    aA.x  = fmaf(a.x,a.x,aA.x);  aA.y  = fmaf(a.y,a.y,aA.y);
    aA.z  = fmaf(a.z,a.z,aA.z);  aA.w  = fmaf(a.w,a.w,aA.w);
    aBx.x = fmaf(a.x,a.y,aBx.x); aBx.y = fmaf(a.y,a.z,aBx.y);
    aBx.z = fmaf(a.z,a.w,aBx.z); aBx.w = fmaf(a.w,axn,aBx.w);
    aBy.x = fmaf(a.x,b.x,aBy.x); aBy.y = fmaf(a.y,b.y,aBy.y);
    aBy.z = fmaf(a.z,b.z,aBy.z); aBy.w = fmaf(a.w,b.w,aBy.w);
    aBd1.x= fmaf(a.x,b.y,aBd1.x);aBd1.y= fmaf(a.y,b.z,aBd1.y);
    aBd1.z= fmaf(a.z,b.w,aBd1.z);aBd1.w= fmaf(a.w,bxn,aBd1.w);
    aBd2.x= fmaf(a.y,b.x,aBd2.x);aBd2.y= fmaf(a.z,b.y,aBd2.y);
    aBd2.z= fmaf(a.w,b.z,aBd2.z);aBd2.w= fmaf(axn,b.w,aBd2.w);
  }
  float* g0 = gram + (((size_t)bn*HW_ + (size_t)r*W_ + col)<<3);
  float4 lo,hi;
  lo.x=aA.x; lo.y=aBx.x; lo.z=aBy.x; lo.w=aBd1.x; hi.x=aBd2.x; hi.y=0; hi.z=0; hi.w=0;
  *reinterpret_cast<float4*>(g0+ 0)=lo; *reinterpret_cast<float4*>(g0+ 4)=hi;
  lo.x=aA.y; lo.y=aBx.y; lo.z=aBy.y; lo.w=aBd1.y; hi.x=aBd2.y;
  *reinterpret_cast<float4*>(g0+ 8)=lo; *reinterpret_cast<float4*>(g0+12)=hi;
  lo.x=aA.z; lo.y=aBx.z; lo.z=aBy.z; lo.w=aBd1.z; hi.x=aBd2.z;
  *reinterpret_cast<float4*>(g0+16)=lo; *reinterpret_cast<float4*>(g0+20)=hi;
  lo.x=aA.w; lo.y=aBx.w; lo.z=aBy.w; lo.w=aBd1.w; hi.x=aBd2.w;
  *reinterpret_cast<float4*>(g0+24)=lo; *reinterpret_cast<float4*>(g0+28)=hi;
}

// ---------- K1b: warp + stats from Gram records ----------
__global__ __launch_bounds__(256) void k_warp2(
  const float* __restrict__ psm, const float* __restrict__ nam,
  const float* __restrict__ gram,
  float* __restrict__ vis, float* __restrict__ scraw, float* __restrict__ sfull,
  float* __restrict__ energy)
{
  int w = threadIdx.x, h = blockIdx.x, bn = blockIdx.y;
  int b = bn/NA, n = bn - b*NA;
  const float* M = nam + (size_t)(b*NA*NA + n)*6;
  float px,py; proj_pt(M[0],M[1],M[2],M[3],M[4],M[5],h,w,px,py);
  float x0f=floorf(px), y0f=floorf(py);
  float wx1=px-x0f, wx0=1.f-wx1, wy1=py-y0f, wy0=1.f-wy1;
  int x0=(int)x0f, y0=(int)y0f, x1=x0+1, y1=y0+1;
  bool vx0=(x0>=0)&&(x0<W_), vx1=(x1>=0)&&(x1<W_);
  bool vy0=(y0>=0)&&(y0<H_), vy1=(y1>=0)&&(y1<H_);
  int cx0=min(max(x0,0),W_-1), cx1=min(max(x1,0),W_-1);
  int cy0=min(max(y0,0),H_-1), cy1=min(max(y1,0),H_-1);
  float w00=(vy0&&vx0)?(wy0*wx0):0.f;
  float w01=(vy0&&vx1)?(wy0*wx1):0.f;
  float w10=(vy1&&vx0)?(wy1*wx0):0.f;
  float w11=(vy1&&vx1)?(wy1*wx1):0.f;
  int i00=cy0*W_+cx0, i01=cy0*W_+cx1, i10=cy1*W_+cx0, i11=cy1*W_+cx1;
  float vv = w00+w01+w10+w11;

  const float* p0 = psm + ((size_t)bn*2+0)*HW_;
  const float* p1 = psm + ((size_t)bn*2+1)*HW_;
  float c0 = w00*p0[i00]+w01*p0[i01]+w10*p0[i10]+w11*p0[i11];
  float c1 = w00*p1[i00]+w01*p1[i01]+w10*p1[i10]+w11*p1[i11];

  const float* G = gram + ((size_t)bn*HW_<<3);
  float4 R00 = *reinterpret_cast<const float4*>(G + ((size_t)i00<<3)); // A,Bx,By,D1
  float  D2  = G[((size_t)i00<<3)+4];
  float4 R01 = *reinterpret_cast<const float4*>(G + ((size_t)i01<<3));
  float4 R10 = *reinterpret_cast<const float4*>(G + ((size_t)i10<<3));
  float  A11 = G[(size_t)i11<<3];
  float e = w00*w00*R00.x + w01*w01*R01.x + w10*w10*R10.x + w11*w11*A11
          + 2.0f*( w00*w01*R00.y + w10*w11*R10.y
                 + w00*w10*R00.z + w01*w11*R01.z
                 + w00*w11*R00.w + w01*w10*D2 );

  size_t idx = (size_t)bn*HW_ + (size_t)h*W_ + w;
  vis[idx]=vv;
  scraw[idx]=fmaxf(sigmoidf_(c0), sigmoidf_(c1));
  sfull[idx]=(clip01(c0)+clip01(c1))*0.5f;
  energy[idx]=e*(1.0f/64.0f);
}

// ---------- K1-mono (fallback if ws too small): R7 proven kernel ----------
#define TWm    32
#define THm    16
#define CAPm   2048
#define TRIPSm 2
#define NBUFm  3
__global__ __launch_bounds__(256) void k_warp_stats_mono(
  const float* __restrict__ x, const float* __restrict__ psm, const float* __restrict__ nam,
  float* __restrict__ vis, float* __restrict__ scraw, float* __restrict__ sfull,
  float* __restrict__ energy)
{
  __shared__ __align__(16) float smem[NBUFm][CAPm];
  int tid = threadIdx.x;
  int tx = blockIdx.x, ty = blockIdx.y, bn = blockIdx.z;
  int b = bn/NA, n = bn - b*NA;
  const float* M = nam + (size_t)(b*NA*NA + n)*6;
  float M0=M[0],M1=M[1],M2=M[2],M3=M[3],M4=M[4],M5=M[5];
  int tw0 = tx*TWm, th0 = ty*THm;
  int r  = tid>>4;
  int cb = (tid&15)<<1;
  int h  = th0 + r;
  int w0 = tw0 + cb;
  float pxa,pya,pxb,pyb,pxc,pyc,pxd,pyd;
  proj_pt(M0,M1,M2,M3,M4,M5, th0,       tw0,       pxa,pya);
  proj_pt(M0,M1,M2,M3,M4,M5, th0,       tw0+TWm-1, pxb,pyb);
  proj_pt(M0,M1,M2,M3,M4,M5, th0+THm-1, tw0,       pxc,pyc);
  proj_pt(M0,M1,M2,M3,M4,M5, th0+THm-1, tw0+TWm-1, pxd,pyd);
  float pxmin=fminf(fminf(pxa,pxb),fminf(pxc,pxd));
  float pxmax=fmaxf(fmaxf(pxa,pxb),fmaxf(pxc,pxd));
  float pymin=fminf(fminf(pya,pyb),fminf(pyc,pyd));
  float pymax=fmaxf(fmaxf(pya,pyb),fmaxf(pyc,pyd));
  int xs = min(max((int)floorf(pxmin)-1, 0), W_-1);
  int xe = min(max((int)floorf(pxmax)+2, 0), W_-1);
  int ys = min(max((int)floorf(pymin)-1, 0), H_-1);
  int ye = min(max((int)floorf(pymax)+2, 0), H_-1);
  int xs4 = xs & ~3;
  int bwid = xe - xs4 + 1, bh = ye - ys + 1;
  int nck = (bwid+3)>>2;
  int bwp = nck<<2;
  int E2 = bh*bwp;
  bool ok = (E2 <= CAPm);
  float vvv[2], w00_[2],w01_[2],w10_[2],w11_[2];
  int   gx0[2],gx1[2],gy0c[2],gy1c[2];
  int   rx0[2]; bool vx0f[2];
  #pragma unroll
  for (int k=0;k<2;++k){
    float px,py; proj_pt(M0,M1,M2,M3,M4,M5, h, w0+k, px,py);
    float x0f=floorf(px), y0f=floorf(py);
    float wx1=px-x0f, wx0=1.f-wx1, wy1=py-y0f, wy0=1.f-wy1;
    int x0=(int)x0f, y0=(int)y0f, x1=x0+1, y1=y0+1;
    bool vx0=(x0>=0)&&(x0<W_), vx1=(x1>=0)&&(x1<W_);
    bool vy0=(y0>=0)&&(y0<H_), vy1=(y1>=0)&&(y1<H_);
    float w00=(vy0&&vx0)?(wy0*wx0):0.f;
    float w01=(vy0&&vx1)?(wy0*wx1):0.f;
    float w10=(vy1&&vx0)?(wy1*wx0):0.f;
    float w11=(vy1&&vx1)?(wy1*wx1):0.f;
    w00_[k]=w00; w01_[k]=w01; w10_[k]=w10; w11_[k]=w11;
    vvv[k]=w00+w01+w10+w11;
    gx0[k]=min(max(x0,0),W_-1); gx1[k]=min(max(x1,0),W_-1);
    gy0c[k]=min(max(y0,0),H_-1); gy1c[k]=min(max(y1,0),H_-1);
    rx0[k]=x0; vx0f[k]=vx0;
  }
  size_t idx = (size_t)bn*HW_ + (size_t)h*W_ + w0;
  float acc[2] = {0.f,0.f};
  int srcoff[TRIPSm]; int ldsbase = (tid>>6)<<6;
  const float* xb0 = x + (size_t)bn*NC*HW_ + (size_t)ys*W_ + xs4;
  if (ok){
    int totq = bh*nck;
    unsigned magic = (unsigned)((0x100000000ULL + (unsigned)nck - 1) / (unsigned)nck);
    int colcap = (W_-4) - xs4;
    #pragma unroll
    for (int k=0;k<TRIPSm;++k){
      int qq = min(tid + (k<<8), totq-1);
      int row = (int)__umulhi((unsigned)qq, magic);
      int col = (qq - row*nck)<<2;
      srcoff[k] = row*W_ + min(col, colcap);
    }
  }
  auto issue = [&](int ch, int bsel){
    const float* src = xb0 + (size_t)ch*HW_;
    #pragma unroll
    for (int k=0;k<TRIPSm;++k){
      __builtin_amdgcn_global_load_lds(
        (const __attribute__((address_space(1))) void*)(src + srcoff[k]),
        (__attribute__((address_space(3))) void*)&smem[bsel][(ldsbase + (k<<8))<<2],
        16, 0, 0);
    }
  };
  if (ok){ issue(0,0); issue(1,1); }
  {
    const float* p0 = psm + ((size_t)bn*2+0)*HW_;
    const float* p1 = psm + ((size_t)bn*2+1)*HW_;
    #pragma unroll
    for (int k=0;k<2;++k){
      int o00=gy0c[k]*W_+gx0[k], o01=gy0c[k]*W_+gx1[k];
      int o10=gy1c[k]*W_+gx0[k], o11=gy1c[k]*W_+gx1[k];
      float c0 = w00_[k]*p0[o00]+w01_[k]*p0[o01]+w10_[k]*p0[o10]+w11_[k]*p0[o11];
      float c1 = w00_[k]*p1[o00]+w01_[k]*p1[o01]+w10_[k]*p1[o10]+w11_[k]*p1[o11];
      vis[idx+k]   = vvv[k];
      scraw[idx+k] = fmaxf(sigmoidf_(c0), sigmoidf_(c1));
      sfull[idx+k] = (clip01(c0)+clip01(c1))*0.5f;
    }
  }
  if (ok){
    int a0[2],a1[2]; float e0[2],e1[2],f0[2],f1[2];
    #pragma unroll
    for (int k=0;k<2;++k){
      int bc = min(max(rx0[k]-xs4,0), bwp-1);
      a0[k] = (gy0c[k]-ys)*bwp + bc;
      a1[k] = (gy1c[k]-ys)*bwp + bc;
      bool v0 = vx0f[k];
      e0[k] = v0 ? w00_[k] : w01_[k];
      e1[k] = v0 ? w01_[k] : 0.f;
      f0[k] = v0 ? w10_[k] : w11_[k];
      f1[k] = v0 ? w11_[k] : 0.f;
    }
    #pragma unroll 1
    for (int c=0;c<NC;++c){
      asm volatile("s_waitcnt vmcnt(2)" ::: "memory"); SBAR;
      __builtin_amdgcn_s_barrier(); SBAR;
      {
        int nc2 = c+2 < NC ? c+2 : NC-1;
        issue(nc2, (c+2)%NBUFm);
      }
      const float* B = smem[c%NBUFm];
      #pragma unroll
      for (int k=0;k<2;++k){
        float r00=B[a0[k]], r01=B[a0[k]+1];
        float r10=B[a1[k]], r11=B[a1[k]+1];
        float v = e0[k]*r00 + e1[k]*r01 + f0[k]*r10 + f1[k]*r11;
        acc[k] += v*v;
      }
    }
    asm volatile("s_waitcnt vmcnt(0)" ::: "memory");
  } else {
    const float* xb = x + (size_t)bn*NC*HW_;
    int go00[2],go01[2],go10[2],go11[2];
    #pragma unroll
    for (int k=0;k<2;++k){
      go00[k]=gy0c[k]*W_+gx0[k]; go01[k]=gy0c[k]*W_+gx1[k];
      go10[k]=gy1c[k]*W_+gx0[k]; go11[k]=gy1c[k]*W_+gx1[k];
    }
    for (int c=0;c<NC;++c){
      const float* pc = xb + (size_t)c*HW_;
      #pragma unroll
      for (int k=0;k<2;++k){
        float v = w00_[k]*pc[go00[k]] + w01_[k]*pc[go01[k]]
                + w10_[k]*pc[go10[k]] + w11_[k]*pc[go11[k]];
        acc[k] += v*v;
      }
    }
  }
  #pragma unroll
  for (int k=0;k<2;++k) energy[idx+k] = acc[k]*(1.0f/64.0f);
}

// ---------- K3: radix-select, ONE BLOCK PER (image, rank); count computed in-block ----------
#define OS_T 1024
__global__ __launch_bounds__(1024) void k_select(
    const float* __restrict__ energy, const float* __restrict__ scraw,
    const float* __restrict__ ppre, const float* __restrict__ vis,
    float* __restrict__ statsE, float* __restrict__ statsC, float* __restrict__ statsP,
    int mode)
{
  __shared__ int hist[16*256];
  __shared__ int cum[256];
  __shared__ unsigned s_pre;
  __shared__ int s_rk;
  __shared__ int s_cnt;
  int tid = threadIdx.x;
  int t = blockIdx.x;

  const float* d; const float* m; float* stats; int img, r;
  if (mode==0){
    bool isC = (t>=96); int tt = isC ? t-96 : t;
    if (tt<80){ img=tt>>2; r=tt&3; } else { int j=tt-80; img=(j>>2)*NA; r=4+(j&3); }
    d = (isC?scraw:energy) + (size_t)img*HW_;
    m = vis + (size_t)img*HW_;
    stats = isC?statsC:statsE;
  } else {
    img = t>>2; r = t&3;
    d = ppre + (size_t)img*HW_;
    m = vis + (size_t)(img*NA)*HW_;
    stats = statsP;
  }

  if (tid==0) s_cnt = 0;
  __syncthreads();

  unsigned key[32];
  int cc = 0;
  #pragma unroll
  for (int k=0;k<32;++k){
    int i = tid + (k<<10);
    unsigned u = __float_as_uint(d[i]);
    unsigned kk = (u & 0x80000000u) ? ~u : (u|0x80000000u);
    bool valid = (m[i] > 0.f);
    key[k] = valid ? kk : 0xFFFFFFFFu;
    cc += valid ? 1 : 0;
  }
  #pragma unroll
  for (int off=32;off;off>>=1) cc += __shfl_down(cc,off);
  if ((tid&63)==0) atomicAdd(&s_cnt, cc);
  __syncthreads();
  int cnt = s_cnt;
  int cm1 = cnt>0 ? cnt-1 : 0;
  float p2 = 0.2f*(float)cm1, p8 = 0.8f*(float)cm1;
  int l2=(int)floorf(p2), h2=(int)ceilf(p2), l8=(int)floorf(p8), h8=(int)ceilf(p8);
  int rank;
  switch(r){
    case 0: rank=l2; break;      case 1: rank=h2; break;
    case 2: rank=l8; break;      case 3: rank=h8; break;
    case 4: rank=cm1-l2; break;  case 5: rank=cm1-h2; break;
    case 6: rank=cm1-l8; break;  default: rank=cm1-h8; break;
  }
  if (tid==0){ s_pre=0u; s_rk=rank; }
  int slice = tid & 15;
  #pragma unroll
  for (int round=0; round<4; ++round){
    const int shift = 24 - 8*round;
    for (int i=tid;i<16*256;i+=OS_T) hist[i]=0;
    __syncthreads();
    unsigned pre = s_pre;
    if (round==0){
      #pragma unroll
      for (int k=0;k<32;++k)
        atomicAdd(&hist[slice*256 + (key[k]>>24)], 1);
    } else {
      #pragma unroll
      for (int k=0;k<32;++k)
        if ((key[k]>>(shift+8)) == pre)
          atomicAdd(&hist[slice*256 + ((key[k]>>shift)&255u)], 1);
    }
    __syncthreads();
    if (tid<256){
      int tt2=0;
      #pragma unroll
      for (int s=0;s<16;++s) tt2 += hist[s*256+tid];
      cum[tid]=tt2;
    }
    __syncthreads();
    if (tid<64){
      int c0=cum[4*tid+0],c1=cum[4*tid+1],c2=cum[4*tid+2],c3=cum[4*tid+3];
      int i0=c0, i1=i0+c1, i2=i1+c2, i3=i2+c3;
      int tot=i3, scan=tot;
      #pragma unroll
      for (int off=1;off<64;off<<=1){ int v=__shfl_up(scan,off); if (tid>=off) scan+=v; }
      int base = scan-tot;
      int rk = s_rk; unsigned pr = s_pre;
      int b0=base, b1=base+i0, b2=base+i1, b3=base+i2, e3=base+i3;
      if      (rk>=b0 && rk<b1){ s_pre=(pr<<8)|(unsigned)(4*tid+0); s_rk=rk-b0; }
      else if (rk>=b1 && rk<b2){ s_pre=(pr<<8)|(unsigned)(4*tid+1); s_rk=rk-b1; }
      else if (rk>=b2 && rk<b3){ s_pre=(pr<<8)|(unsigned)(4*tid+2); s_rk=rk-b2; }
      else if (rk>=b3 && rk<e3){ s_pre=(pr<<8)|(unsigned)(4*tid+3); s_rk=rk-b3; }
    }
    __syncthreads();
  }
  if (tid==0){
    unsigned k = s_pre;
    unsigned u = (k & 0x80000000u) ? (k & 0x7FFFFFFFu) : ~k;
    stats[img*16 + 1 + r] = __uint_as_float(u);
    if (r==0) stats[img*16] = (float)cnt;
  }
}

// ---------- K4: per-batch scalar params from order stats ----------
__global__ void k_params(const float* __restrict__ statsE, const float* __restrict__ statsC,
                         float* __restrict__ params){
  int b = threadIdx.x;
  if (b>=NB) return;
  float* pr = params + b*32;
  for (int n=0;n<NA;++n){
    const float* sE = statsE + (size_t)(b*NA+n)*16;
    const float* sC = statsC + (size_t)(b*NA+n)*16;
    int cE=(int)sE[0], cC=(int)sC[0];
    pr[n]    = quantv(cE,0.2f,sE[1],sE[2]);
    pr[5+n]  = quantv(cE,0.8f,sE[3],sE[4]);
    pr[10+n] = quantv(cC,0.2f,sC[1],sC[2]);
    pr[15+n] = quantv(cC,0.8f,sC[3],sC[4]);
  }
  const float* sE0 = statsE + (size_t)(b*NA)*16;
  const float* sC0 = statsC + (size_t)(b*NA)*16;
  float loe=pr[0], hie=pr[5], loc=pr[10], hic=pr[15];
  float de_lo=0.f,de_hi=0.f,ke=0.f, dc_lo=0.f,dc_hi=0.f,kc=0.f;
  int c0=(int)sE0[0];
  if (c0>0){
    int cm1=c0-1;
    float pos2=0.2f*(float)cm1, pos8=0.8f*(float)cm1;
    float f2=pos2-floorf(pos2), f8=pos8-floorf(pos8);
    float a,bb;
    a=1.f-ge_f(sE0[5],loe,hie); bb=1.f-ge_f(sE0[6],loe,hie); de_lo=a+f2*(bb-a);
    a=1.f-ge_f(sE0[7],loe,hie); bb=1.f-ge_f(sE0[8],loe,hie); de_hi=a+f8*(bb-a);
    a=ge_f(sE0[1],loe,hie);     bb=ge_f(sE0[2],loe,hie);     ke  =a+f2*(bb-a);
  }
  int c0c=(int)sC0[0];
  if (c0c>0){
    int cm1=c0c-1;
    float pos2=0.2f*(float)cm1, pos8=0.8f*(float)cm1;
    float f2=pos2-floorf(pos2), f8=pos8-floorf(pos8);
    float a,bb;
    a=1.f-ge_f(sC0[5],loc,hic); bb=1.f-ge_f(sC0[6],loc,hic); dc_lo=a+f2*(bb-a);
    a=1.f-ge_f(sC0[7],loc,hic); bb=1.f-ge_f(sC0[8],loc,hic); dc_hi=a+f8*(bb-a);
    a=ge_f(sC0[1],loc,hic);     bb=ge_f(sC0[2],loc,hic);     kc  =a+f2*(bb-a);
  }
  pr[20]=de_lo; pr[21]=de_hi; pr[22]=dc_lo; pr[23]=dc_hi; pr[24]=ke; pr[25]=kc;
}

// ---------- K5: pattern-gate P (pre-normalization) ----------
__global__ __launch_bounds__(256) void k_ppre(
  const float* __restrict__ vis, const float* __restrict__ scraw,
  const float* __restrict__ energy, const float* __restrict__ params,
  float* __restrict__ ppre)
{
  int w=threadIdx.x, h=blockIdx.x, b=blockIdx.y;
  int p=h*W_+w;
  const float* pr = params + b*32;
  size_t base = (size_t)b*NA*HW_ + p;
  float se[NA], sc[NA], vf[NA];
  #pragma unroll
  for (int n=0;n<NA;++n){
    float vv = vis[base + (size_t)n*HW_];
    float f = (vv>0.f)?1.f:0.f; vf[n]=f;
    se[n] = clip01((energy[base+(size_t)n*HW_]-pr[n])/(pr[5+n]-pr[n]+EPS_))*f;
    sc[n] = clip01((scraw[base+(size_t)n*HW_]-pr[10+n])/(pr[15+n]-pr[10+n]+EPS_))*f;
  }
  float sup = 0.f;
  #pragma unroll
  for (int n=1;n<NA;++n) sup += (0.8f*se[n]+0.2f*sc[n])*vf[n];
  sup *= 0.25f;
  float de = clip01(((1.f-se[0])-pr[20])/(pr[21]-pr[20]+EPS_))*vf[0];
  float dc = clip01(((1.f-sc[0])-pr[22])/(pr[23]-pr[22]+EPS_))*vf[0];
  float D  = (0.7f*de + 0.3f*dc)*vf[0];
  bool ke = (se[0] <= pr[24]) && (vf[0]>0.f);
  bool kc = (sc[0] <= pr[25]) && (vf[0]>0.f);
  float kem = (ke&&kc)?1.f:0.f;
  ppre[(size_t)b*HW_+p] = D*sup*(1.f-kem);
}

// ---------- K6: winner argmax + owner/comm bits ----------
__global__ __launch_bounds__(256) void k_owner(
  const float* __restrict__ vis, const float* __restrict__ scraw,
  const float* __restrict__ sfull, const float* __restrict__ ppre,
  const float* __restrict__ statsP, int* __restrict__ omask)
{
  int w=threadIdx.x,h=blockIdx.x,b=blockIdx.y;
  int p=h*W_+w;
  const float* sP = statsP + b*16;
  int cntP=(int)sP[0];
  float plo = quantv(cntP,0.2f,sP[1],sP[2]);
  float phi = quantv(cntP,0.8f,sP[3],sP[4]);
  size_t base=(size_t)b*NA*HW_+p;
  float vf0 = (vis[base]>0.f)?1.f:0.f;
  float Pf = clip01((ppre[(size_t)b*HW_+p]-plo)/(phi-plo+EPS_))*vf0;
  float gate = 0.1f + 0.9f*Pf;
  int winner=0; float best=-1.f;
  int cbits=0;
  #pragma unroll
  for (int n=0;n<NA;++n){
    float vv = vis[base+(size_t)n*HW_];
    float f=(vv>0.f)?1.f:0.f;
    float s = ((sfull[base+(size_t)n*HW_]*f)*gate)*f;
    if (s>best){best=s;winner=n;}
    bool cm = (n==0) || (scraw[base+(size_t)n*HW_] > 0.5f);
    if (cm) cbits |= 1<<n;
  }
  int ob = ((cbits>>winner)&1) ? (1<<winner) : 0;
  omask[(size_t)b*HW_+p] = ob | (cbits<<8);
}

// ---------- K7: 3x3 dilation, final mask, effective-rate count ----------
__global__ __launch_bounds__(256) void k_final(
  const int* __restrict__ omask, int* __restrict__ fmask, int* __restrict__ counter)
{
  int w=threadIdx.x,h=blockIdx.x,b=blockIdx.y;
  int p=h*W_+w;
  const int* om = omask + (size_t)b*HW_;
  int ow=0;
  #pragma unroll
  for (int dy=-1;dy<=1;++dy){
    int y=h+dy; if (y<0||y>=H_) continue;
    #pragma unroll
    for (int dx=-1;dx<=1;++dx){
      int x=w+dx; if (x<0||x>=W_) continue;
      ow |= om[y*W_+x];
    }
  }
  int cbits=(om[p]>>8)&31;
  int fin = ow & cbits & 31;
  fmask[(size_t)b*HW_+p]=fin;
  int cn = __popc(fin & 30);
  for (int off=32;off;off>>=1) cn += __shfl_down(cn,off);
  if ((threadIdx.x&63)==0) atomicAdd(counter, cn);
}

// ---------- K8: masked-max warped output (R12 proven scalar-gather form) ----------
__global__ __launch_bounds__(256, 2) void k_out(
  const float* __restrict__ x, const float* __restrict__ nam,
  const int* __restrict__ fmask, const int* __restrict__ counter,
  float* __restrict__ out, int out_size)
{
  int w=threadIdx.x, h=blockIdx.x, b=blockIdx.y;
  int p=h*W_+w;
  int fin = fmask[(size_t)b*HW_+p] & 31;
  float init = (__popc(fin)<NA) ? 0.f : -__builtin_inff();
  Taps tp[NA];
  #pragma unroll
  for (int n=0;n<NA;++n) tp[n] = make_taps(nam + (size_t)(b*NA*NA+n)*6, h, w);
  #pragma unroll 1
  for (int cb=0; cb<NC/16; ++cb){
    float m[16];
    #pragma unroll
    for (int c=0;c<16;++c) m[c]=init;
    #pragma unroll
    for (int n=0;n<NA;++n){
      if (!((fin>>n)&1)) continue;
      const float* pc = x + ((size_t)(b*NA+n)*NC + cb*16)*HW_;
      float a00[16],a01[16],a10[16],a11[16];
      #pragma unroll
      for (int c=0;c<16;++c){
        a00[c]=pc[tp[n].o00]; a01[c]=pc[tp[n].o01]; a10[c]=pc[tp[n].o10]; a11[c]=pc[tp[n].o11];
        pc += HW_;
      }
      #pragma unroll
      for (int c=0;c<16;++c){
        float v = tp[n].w00*a00[c] + tp[n].w01*a01[c] + tp[n].w10*a10[c] + tp[n].w11*a11[c];
        m[c] = fmaxf(m[c], v);
      }
    }
    #pragma unroll
    for (int c=0;c<16;++c)
      out[(((size_t)b*NC + cb*16 + c)*H_+h)*W_+w] = m[c];
  }
  if (b==0 && h==0 && w==0)
    out[out_size-1] = (float)(*counter) * (1.0f/524288.0f);  // /(B*(N-1)*H*W)
}

extern "C" void kernel_launch(void* const* d_in, const int* in_sizes, int n_in,
                              void* d_out, int out_size, void* d_ws, size_t ws_size,
                              hipStream_t stream) {
  (void)in_sizes; (void)n_in;
  const float* x   = (const float*)d_in[0];
  const float* psm = (const float*)d_in[1];
  const float* nam = (const float*)d_in[3];
  float* out = (float*)d_out;

  float* ws     = (float*)d_ws;
  float* vis    = ws;                         // 20*HW
  float* scraw  = vis    + (size_t)NIMG*HW_;  // 20*HW
  float* sfull  = scraw  + (size_t)NIMG*HW_;  // 20*HW
  float* energy = sfull  + (size_t)NIMG*HW_;  // 20*HW
  float* ppre   = energy + (size_t)NIMG*HW_;  // 4*HW
  float* statsE = ppre   + (size_t)NB*HW_;    // 20*16
  float* statsC = statsE + NIMG*16;           // 20*16
  float* statsP = statsC + NIMG*16;           // 4*16
  float* params = statsP + NB*16;             // 4*32
  int*   omask  = (int*)(params + NB*32);     // 4*HW
  int*   fmask  = omask + (size_t)NB*HW_;     // 4*HW
  int*   counter= fmask + (size_t)NB*HW_;     // 1
  float* gram   = (float*)(counter + 64);     // 20*HW*8 (interleaved records)
  size_t need = (size_t)((gram + ((size_t)NIMG*HW_<<3)) - ws) * sizeof(float);

  hipLaunchKernelGGL(k_init, dim3(1), dim3(64), 0, stream, counter);
  if (ws_size >= need){
    hipLaunchKernelGGL(k_gram, dim3(NIMG*H_), dim3(64), 0, stream, x, gram);
    hipLaunchKernelGGL(k_warp2, dim3(H_,NIMG), dim3(W_), 0, stream,
                       psm, nam, gram, vis, scraw, sfull, energy);
  } else {
    hipLaunchKernelGGL(k_warp_stats_mono, dim3(W_/TWm, H_/THm, NIMG), dim3(256), 0, stream,
                       x, psm, nam, vis, scraw, sfull, energy);
  }
  hipLaunchKernelGGL(k_select, dim3(192), dim3(OS_T), 0, stream,
                     energy, scraw, ppre, vis, statsE, statsC, statsP, 0);
  hipLaunchKernelGGL(k_params, dim3(1), dim3(64), 0, stream, statsE, statsC, params);
  hipLaunchKernelGGL(k_ppre, dim3(H_,NB), dim3(W_), 0, stream,
                     vis, scraw, energy, params, ppre);
  hipLaunchKernelGGL(k_select, dim3(16), dim3(OS_T), 0, stream,
                     energy, scraw, ppre, vis, statsE, statsC, statsP, 1);
  hipLaunchKernelGGL(k_owner, dim3(H_,NB), dim3(W_), 0, stream,
                     vis, scraw, sfull, ppre, statsP, omask);
  hipLaunchKernelGGL(k_final, dim3(H_,NB), dim3(W_), 0, stream, omask, fmask, counter);
  hipLaunchKernelGGL(k_out, dim3(H_,NB), dim3(W_), 0, stream,
                     x, nam, fmask, counter, out, out_size);
}